// Round 6
// baseline (517.571 us; speedup 1.0000x reference)
//
#include <hip/hip_runtime.h>
#include <hip/hip_bf16.h>
#include <stdint.h>

#define B_  256
#define L_  256
#define S_  253
#define D_  768
#define H_  128

typedef __bf16 bf16x8 __attribute__((ext_vector_type(8)));
typedef float  f32x4  __attribute__((ext_vector_type(4)));

__device__ __forceinline__ ushort f2bf(float f) {
  union { float f; uint32_t u; } v; v.f = f;
  uint32_t r = v.u + 0x7FFFu + ((v.u >> 16) & 1u);  // RNE
  return (ushort)(r >> 16);
}

// 8 f32 -> 8 bf16 in-register (v_cvt_pk_bf16_f32: src0 -> low16, src1 -> high16)
__device__ __forceinline__ bf16x8 cvt8(f32x4 a, f32x4 b) {
  union { uint32_t u[4]; bf16x8 v; } r;
  asm("v_cvt_pk_bf16_f32 %0, %1, %2" : "=v"(r.u[0]) : "v"(a[0]), "v"(a[1]));
  asm("v_cvt_pk_bf16_f32 %0, %1, %2" : "=v"(r.u[1]) : "v"(a[2]), "v"(a[3]));
  asm("v_cvt_pk_bf16_f32 %0, %1, %2" : "=v"(r.u[2]) : "v"(b[0]), "v"(b[1]));
  asm("v_cvt_pk_bf16_f32 %0, %1, %2" : "=v"(r.u[3]) : "v"(b[2]), "v"(b[3]));
  return r.v;
}

__device__ __forceinline__ void gload16(const void* g, void* l) {
  __builtin_amdgcn_global_load_lds((const __attribute__((address_space(1))) void*)g,
                                   (__attribute__((address_space(3))) void*)l,
                                   16, 0, 0);
}

// Bank swizzle (verified R5: conflicts -> 0). LDS rows of 32 ushort = 4 slots
// of 16 B; stored slot s at row r holds global slot s ^ ((r>>1)&3).
#define SRC_OFF(l) ((((l) & 3) ^ (((l) >> 3) & 3)) * 8)
#define RD_OFF(l)  (((((l) >> 4) ^ (((l) >> 1) & 3))) * 8)

// ---------------- k0: Mt[i][j] = scale * sum_t WK[i,t] * WQ[j,t] (bf16) -----
__global__ __launch_bounds__(256) void k_mt(const float* __restrict__ WK,
                                            const float* __restrict__ WQ,
                                            ushort* __restrict__ Mt) {
  const float scale = 0.03608439182435161f;  // 1/sqrt(768)
  int bid = blockIdx.x;
  int i0 = (bid / 3) * 4;
  int j  = (bid % 3) * 256 + threadIdx.x;
  const float4* wq  = (const float4*)(WQ + (size_t)j * D_);
  const float4* wk0 = (const float4*)(WK + (size_t)(i0 + 0) * D_);
  const float4* wk1 = (const float4*)(WK + (size_t)(i0 + 1) * D_);
  const float4* wk2 = (const float4*)(WK + (size_t)(i0 + 2) * D_);
  const float4* wk3 = (const float4*)(WK + (size_t)(i0 + 3) * D_);
  float a0 = 0.f, a1 = 0.f, a2 = 0.f, a3 = 0.f;
#pragma unroll 4
  for (int t = 0; t < D_ / 4; ++t) {
    float4 q = wq[t];
    float4 k0 = wk0[t], k1 = wk1[t], k2 = wk2[t], k3 = wk3[t];
    a0 += q.x * k0.x + q.y * k0.y + q.z * k0.z + q.w * k0.w;
    a1 += q.x * k1.x + q.y * k1.y + q.z * k1.z + q.w * k1.w;
    a2 += q.x * k2.x + q.y * k2.y + q.z * k2.z + q.w * k2.w;
    a3 += q.x * k3.x + q.y * k3.y + q.z * k3.z + q.w * k3.w;
  }
  Mt[(size_t)(i0 + 0) * D_ + j] = f2bf(a0 * scale);
  Mt[(size_t)(i0 + 1) * D_ + j] = f2bf(a1 * scale);
  Mt[(size_t)(i0 + 2) * D_ + j] = f2bf(a2 * scale);
  Mt[(size_t)(i0 + 3) * D_ + j] = f2bf(a3 * scale);
}

// ---------------- k1: qm[r][c] = sum_k ctx[r][k] * Mt[c][k]  (bf16 out) -----
// 128x128 tile, BK=64. B (Mt): gload_lds bf16 + swizzle (R5 proven).
// A (ctx): f32 direct-to-register in A-frag layout, cvt_pk in VALU —
// no ctxb pre-pass, no LDS for A. A-loads issue before the barrier so
// their latency rides the B gload drain.
__global__ __launch_bounds__(256) void k_qm(const float* __restrict__ ctx,
                                            const ushort* __restrict__ Mt,
                                            ushort* __restrict__ qm) {
  __shared__ __align__(16) ushort Bs[2][128 * 32];
  int bid0 = blockIdx.x;              // 0..3071
  int xcd = bid0 & 7;
  int idx = bid0 >> 3;                // 0..383
  int bm = xcd * 64 + idx / 6;        // 0..511 (bijective)
  int bn = idx % 6;
  int row0 = bm * 128, col0 = bn * 128;
  int tid = threadIdx.x;
  int w = tid >> 6, l = tid & 63;
  int wr = w >> 1, wc = w & 1;
  int src_off = SRC_OFF(l);
  int rd_off  = RD_OFF(l);

  // A-frag row pointers: lane l covers row m*16+(l&15), k-slot (l>>4)*8
  const float* arow0 = ctx + (size_t)(row0 + wr * 64 + 0 * 16 + (l & 15)) * D_ + (l >> 4) * 8;
  const float* arow1 = arow0 + (size_t)16 * D_;
  const float* arow2 = arow0 + (size_t)32 * D_;
  const float* arow3 = arow0 + (size_t)48 * D_;

  f32x4 acc[4][4];
#pragma unroll
  for (int m = 0; m < 4; ++m)
#pragma unroll
    for (int n = 0; n < 4; ++n) acc[m][n] = (f32x4){0.f, 0.f, 0.f, 0.f};

  for (int kt = 0; kt < D_; kt += 64) {
    if (kt) __syncthreads();
    // B: async global->LDS (bf16, swizzled)
#pragma unroll
    for (int h = 0; h < 2; ++h)
#pragma unroll
      for (int g = 0; g < 2; ++g) {
        int grp = w * 2 + g;
        const ushort* bsrc = Mt + (size_t)(col0 + grp * 16 + (l >> 2)) * D_
                                + kt + h * 32 + src_off;
        gload16(bsrc, (char*)Bs[h] + grp * 1024);
      }
    // A: f32 -> regs (latency overlaps the barrier drain of B)
    f32x4 a0[4][2], a1[4][2];
#pragma unroll
    for (int h = 0; h < 2; ++h) {
      const f32x4* p0 = (const f32x4*)(arow0 + kt + h * 32);
      const f32x4* p1 = (const f32x4*)(arow1 + kt + h * 32);
      const f32x4* p2 = (const f32x4*)(arow2 + kt + h * 32);
      const f32x4* p3 = (const f32x4*)(arow3 + kt + h * 32);
      a0[0][h] = p0[0]; a1[0][h] = p0[1];
      a0[1][h] = p1[0]; a1[1][h] = p1[1];
      a0[2][h] = p2[0]; a1[2][h] = p2[1];
      a0[3][h] = p3[0]; a1[3][h] = p3[1];
    }
    __syncthreads();

#pragma unroll
    for (int h = 0; h < 2; ++h) {
      bf16x8 af[4], bfr[4];
#pragma unroll
      for (int m = 0; m < 4; ++m)
        af[m] = cvt8(a0[m][h], a1[m][h]);
#pragma unroll
      for (int n = 0; n < 4; ++n)
        bfr[n] = *(const bf16x8*)&Bs[h][(wc * 64 + n * 16 + (l & 15)) * 32 + rd_off];
#pragma unroll
      for (int m = 0; m < 4; ++m)
#pragma unroll
        for (int n = 0; n < 4; ++n)
          acc[m][n] = __builtin_amdgcn_mfma_f32_16x16x32_bf16(af[m], bfr[n], acc[m][n], 0, 0, 0);
    }
  }

  int rbase = row0 + wr * 64;
  int cbase = col0 + wc * 64;
#pragma unroll
  for (int m = 0; m < 4; ++m)
#pragma unroll
    for (int n = 0; n < 4; ++n)
#pragma unroll
      for (int i = 0; i < 4; ++i) {
        int rr = rbase + m * 16 + (l >> 4) * 4 + i;
        int cc = cbase + n * 16 + (l & 15);
        qm[(size_t)rr * D_ + cc] = f2bf(acc[m][n][i]);
      }
}

// ---------------- k2: logits -> sigmoid -> * w -> row-sum -> x --------------
// BM=64, BN=256, BK=64, 4 waves (1x4). A (qm): gload_lds bf16 (unchanged).
// B (cand): f32 direct-to-register + cvt, row-clamped at S=253. w = cand.WV
// fused into the loop (wacc per lane), 2x shfl_xor reduce -> each lane holds
// exactly the w for its own epilogue column. k_cand/candb/wbuf eliminated.
__global__ __launch_bounds__(256) void k_attn(const ushort* __restrict__ qm,
                                              const float* __restrict__ cand,
                                              const int* __restrict__ cand_mask,
                                              const int* __restrict__ ctx_mask,
                                              const float* __restrict__ WV,
                                              float* __restrict__ xbuf) {
  __shared__ __align__(16) ushort As[2][64 * 32];
  __shared__ float wv_lds[D_];
  __shared__ float xpart[4][64];
  int bid0 = blockIdx.x;                    // 0..1023
  int nb = (bid0 & 7) * 128 + (bid0 >> 3);  // bijective XCD-chunked remap
  int b = nb >> 2, lt = nb & 3;
  int row0 = lt * 64;
  int tid = threadIdx.x, w = tid >> 6, l = tid & 63;
  int src_off = SRC_OFF(l);
  int rd_off  = RD_OFF(l);

  wv_lds[tid]       = WV[tid];
  wv_lds[tid + 256] = WV[tid + 256];
  wv_lds[tid + 512] = WV[tid + 512];

  // B-frag row pointers (cand rows, clamped to stay in-bounds on padding)
  const float* brow[4];
  int sidx[4];
#pragma unroll
  for (int n = 0; n < 4; ++n) {
    int s = w * 64 + n * 16 + (l & 15);
    sidx[n] = s;
    int sc = s < S_ ? s : S_ - 1;
    brow[n] = cand + ((size_t)b * S_ + sc) * D_ + (l >> 4) * 8;
  }

  f32x4 acc[4][4];
#pragma unroll
  for (int m = 0; m < 4; ++m)
#pragma unroll
    for (int n = 0; n < 4; ++n) acc[m][n] = (f32x4){0.f, 0.f, 0.f, 0.f};
  float wacc[4] = {0.f, 0.f, 0.f, 0.f};

  size_t arow = (size_t)b * 256 + row0;
  __syncthreads();  // wv_lds ready

  for (int kt = 0; kt < D_; kt += 64) {
    if (kt) __syncthreads();
    // A: 1 gload/wave/panel (16 rows each)
#pragma unroll
    for (int h = 0; h < 2; ++h) {
      const ushort* gsrc = qm + (arow + w * 16 + (l >> 2)) * D_ + kt + h * 32 + src_off;
      gload16(gsrc, (char*)As[h] + w * 1024);
    }
    // B: f32 -> regs
    f32x4 b0[4][2], b1[4][2];
#pragma unroll
    for (int n = 0; n < 4; ++n)
#pragma unroll
      for (int h = 0; h < 2; ++h) {
        const f32x4* bp = (const f32x4*)(brow[n] + kt + h * 32);
        b0[n][h] = bp[0];
        b1[n][h] = bp[1];
      }
    __syncthreads();

#pragma unroll
    for (int h = 0; h < 2; ++h) {
      f32x4 wv0 = *(const f32x4*)&wv_lds[kt + h * 32 + (l >> 4) * 8];
      f32x4 wv1 = *(const f32x4*)&wv_lds[kt + h * 32 + (l >> 4) * 8 + 4];
      bf16x8 af[4], bfr[4];
#pragma unroll
      for (int m = 0; m < 4; ++m)
        af[m] = *(const bf16x8*)&As[h][(m * 16 + (l & 15)) * 32 + rd_off];
#pragma unroll
      for (int n = 0; n < 4; ++n) {
        bfr[n] = cvt8(b0[n][h], b1[n][h]);
        wacc[n] += b0[n][h][0] * wv0[0] + b0[n][h][1] * wv0[1]
                 + b0[n][h][2] * wv0[2] + b0[n][h][3] * wv0[3]
                 + b1[n][h][0] * wv1[0] + b1[n][h][1] * wv1[1]
                 + b1[n][h][2] * wv1[2] + b1[n][h][3] * wv1[3];
      }
#pragma unroll
      for (int m = 0; m < 4; ++m)
#pragma unroll
        for (int n = 0; n < 4; ++n)
          acc[m][n] = __builtin_amdgcn_mfma_f32_16x16x32_bf16(af[m], bfr[n], acc[m][n], 0, 0, 0);
    }
  }

  // finish w: reduce over the 4 k-lane-groups, then mask
#pragma unroll
  for (int n = 0; n < 4; ++n) {
    wacc[n] += __shfl_xor(wacc[n], 16, 64);
    wacc[n] += __shfl_xor(wacc[n], 32, 64);
    int s = sidx[n];
    int ok = (s < S_) && (cand_mask[(size_t)b * S_ + s] != 0);
    wacc[n] = ok ? wacc[n] : 0.f;
  }

  float rs[4][4];
#pragma unroll
  for (int m = 0; m < 4; ++m)
#pragma unroll
    for (int i = 0; i < 4; ++i) rs[m][i] = 0.f;

#pragma unroll
  for (int n = 0; n < 4; ++n) {
#pragma unroll
    for (int m = 0; m < 4; ++m)
#pragma unroll
      for (int i = 0; i < 4; ++i) {
        float p = 1.f / (1.f + __expf(-acc[m][n][i]));
        rs[m][i] += p * wacc[n];
      }
  }
#pragma unroll
  for (int m = 0; m < 4; ++m)
#pragma unroll
    for (int i = 0; i < 4; ++i) {
      float v = rs[m][i];
      v += __shfl_xor(v, 1, 64);
      v += __shfl_xor(v, 2, 64);
      v += __shfl_xor(v, 4, 64);
      v += __shfl_xor(v, 8, 64);
      rs[m][i] = v;
    }
  if ((l & 15) == 0) {
#pragma unroll
    for (int m = 0; m < 4; ++m)
#pragma unroll
      for (int i = 0; i < 4; ++i)
        xpart[w][m * 16 + (l >> 4) * 4 + i] = rs[m][i];
  }
  __syncthreads();
  if (tid < 64) {
    float xs = xpart[0][tid] + xpart[1][tid] + xpart[2][tid] + xpart[3][tid];
    int gm = ctx_mask[(size_t)b * 256 + row0 + tid];
    xbuf[(size_t)b * 256 + row0 + tid] = gm ? xs : 0.f;
  }
}

// ---------------- k3: y[b] = (x[b]^T W1 + b1) W2 + b2 ----------------------
__global__ __launch_bounds__(128) void k_mlp(const float* __restrict__ xbuf,
                                             const float* __restrict__ W1,
                                             const float* __restrict__ b1,
                                             const float* __restrict__ W2,
                                             const float* __restrict__ b2,
                                             float* __restrict__ out) {
  int b = blockIdx.x, t = threadIdx.x;
  __shared__ float xl[256];
  __shared__ float hl[128];
  xl[t]       = xbuf[(size_t)b * 256 + t];
  xl[t + 128] = xbuf[(size_t)b * 256 + 128 + t];
  __syncthreads();
  float acc = b1[t];
#pragma unroll 8
  for (int ll = 0; ll < 256; ++ll) acc += xl[ll] * W1[ll * H_ + t];
  hl[t] = acc;
  __syncthreads();
  if (t < 5) {
    float y = b2[t];
#pragma unroll 8
    for (int h = 0; h < H_; ++h) y += hl[h] * W2[h * 5 + t];
    out[(size_t)b * 5 + t] = y;
  }
}

extern "C" void kernel_launch(void* const* d_in, const int* in_sizes, int n_in,
                              void* d_out, int out_size, void* d_ws, size_t ws_size,
                              hipStream_t stream) {
  const float* ctx       = (const float*)d_in[0];
  const float* cand      = (const float*)d_in[1];
  const int*   ctx_mask  = (const int*)d_in[2];
  const int*   cand_mask = (const int*)d_in[3];
  const float* WK        = (const float*)d_in[4];
  const float* WQ        = (const float*)d_in[5];
  const float* WV        = (const float*)d_in[6];
  const float* W1        = (const float*)d_in[7];
  const float* b1        = (const float*)d_in[8];
  const float* W2        = (const float*)d_in[9];
  const float* b2        = (const float*)d_in[10];
  float* out = (float*)d_out;

  char* ws = (char*)d_ws;
  size_t off = 0;
  auto alloc = [&](size_t bytes) {
    void* p = ws + off;
    off += (bytes + 255) & ~(size_t)255;
    return p;
  };
  ushort* Mt   = (ushort*)alloc((size_t)D_ * D_ * 2);        // 1.18 MB
  float*  xbuf = (float*) alloc((size_t)B_ * L_ * 4);        // 256 KB
  ushort* qm   = (ushort*)alloc((size_t)B_ * L_ * D_ * 2);   // 100.7 MB
  (void)ws_size; (void)in_sizes; (void)n_in; (void)out_size;

  k_mt  <<<(D_ / 4) * 3,      256, 0, stream>>>(WK, WQ, Mt);
  k_qm  <<<B_ * L_ / 128 * 6, 256, 0, stream>>>(ctx, Mt, qm);
  k_attn<<<B_ * 4,            256, 0, stream>>>(qm, cand, cand_mask, ctx_mask, WV, xbuf);
  k_mlp <<<B_,                128, 0, stream>>>(xbuf, W1, b1, W2, b2, out);
}

// Round 7
// 372.103 us; speedup vs baseline: 1.3909x; 1.3909x over previous
//
#include <hip/hip_runtime.h>
#include <hip/hip_bf16.h>
#include <stdint.h>

#define B_  256
#define L_  256
#define S_  253
#define SP_ 256   // padded S
#define D_  768
#define H_  128

typedef __bf16 bf16x8 __attribute__((ext_vector_type(8)));
typedef float  f32x4  __attribute__((ext_vector_type(4)));

__device__ __forceinline__ ushort f2bf(float f) {
  union { float f; uint32_t u; } v; v.f = f;
  uint32_t r = v.u + 0x7FFFu + ((v.u >> 16) & 1u);  // RNE
  return (ushort)(r >> 16);
}

__device__ __forceinline__ void gload16(const void* g, void* l) {
  __builtin_amdgcn_global_load_lds((const __attribute__((address_space(1))) void*)g,
                                   (__attribute__((address_space(3))) void*)l,
                                   16, 0, 0);
}

// Bank swizzle (verified R5: SQ_LDS_BANK_CONFLICT -> 0). LDS rows of 32 ushort
// = 4 slots of 16 B; stored slot s at row r holds global slot s ^ ((r>>1)&3).
#define SRC_OFF(l) ((((l) & 3) ^ (((l) >> 3) & 3)) * 8)
#define RD_OFF(l)  (((((l) >> 4) ^ (((l) >> 1) & 3))) * 8)

// ---------------- k0: Mt[i][j] = scale * sum_t WK[i,t] * WQ[j,t] (bf16) -----
__global__ __launch_bounds__(256) void k_mt(const float* __restrict__ WK,
                                            const float* __restrict__ WQ,
                                            ushort* __restrict__ Mt) {
  const float scale = 0.03608439182435161f;  // 1/sqrt(768)
  int bid = blockIdx.x;
  int i0 = (bid / 3) * 4;
  int j  = (bid % 3) * 256 + threadIdx.x;
  const float4* wq  = (const float4*)(WQ + (size_t)j * D_);
  const float4* wk0 = (const float4*)(WK + (size_t)(i0 + 0) * D_);
  const float4* wk1 = (const float4*)(WK + (size_t)(i0 + 1) * D_);
  const float4* wk2 = (const float4*)(WK + (size_t)(i0 + 2) * D_);
  const float4* wk3 = (const float4*)(WK + (size_t)(i0 + 3) * D_);
  float a0 = 0.f, a1 = 0.f, a2 = 0.f, a3 = 0.f;
#pragma unroll 4
  for (int t = 0; t < D_ / 4; ++t) {
    float4 q = wq[t];
    float4 k0 = wk0[t], k1 = wk1[t], k2 = wk2[t], k3 = wk3[t];
    a0 += q.x * k0.x + q.y * k0.y + q.z * k0.z + q.w * k0.w;
    a1 += q.x * k1.x + q.y * k1.y + q.z * k1.z + q.w * k1.w;
    a2 += q.x * k2.x + q.y * k2.y + q.z * k2.z + q.w * k2.w;
    a3 += q.x * k3.x + q.y * k3.y + q.z * k3.z + q.w * k3.w;
  }
  Mt[(size_t)(i0 + 0) * D_ + j] = f2bf(a0 * scale);
  Mt[(size_t)(i0 + 1) * D_ + j] = f2bf(a1 * scale);
  Mt[(size_t)(i0 + 2) * D_ + j] = f2bf(a2 * scale);
  Mt[(size_t)(i0 + 3) * D_ + j] = f2bf(a3 * scale);
}

// ---------------- k1: ctx f32 -> bf16, streaming ---------------------------
__global__ __launch_bounds__(256) void k_ctxb(const float* __restrict__ ctx,
                                              ushort* __restrict__ ctxb) {
  const int64_t n4 = (int64_t)B_ * L_ * D_ / 4;
  int64_t stride = (int64_t)gridDim.x * 256;
  for (int64_t i = (int64_t)blockIdx.x * 256 + threadIdx.x; i < n4; i += stride) {
    float4 c = ((const float4*)ctx)[i];
    ushort4 o;
    o.x = f2bf(c.x); o.y = f2bf(c.y); o.z = f2bf(c.z); o.w = f2bf(c.w);
    ((ushort4*)ctxb)[i] = o;
  }
}

// ---------------- k2: cand -> bf16 (padded), w[b,s] = mask * (cand . WV) ----
__global__ __launch_bounds__(256) void k_cand(const float* __restrict__ cand,
                                              const int* __restrict__ cand_mask,
                                              const float* __restrict__ WV,
                                              ushort* __restrict__ candb,
                                              float* __restrict__ wbuf) {
  int r = blockIdx.x * 4 + (threadIdx.x >> 6);  // padded row id, one wave per row
  int l = threadIdx.x & 63;
  int b = r >> 8, s = r & 255;
  float acc = 0.f;
  ushort* dst = candb + (size_t)r * D_;
  if (s < S_) {
    const float4* src = (const float4*)(cand + ((size_t)b * S_ + s) * D_);
    const float4* wv4 = (const float4*)WV;
#pragma unroll
    for (int i = 0; i < 3; ++i) {
      int d4 = i * 64 + l;
      float4 c = src[d4];
      float4 v = wv4[d4];
      acc += c.x * v.x + c.y * v.y + c.z * v.z + c.w * v.w;
      ushort4 o;
      o.x = f2bf(c.x); o.y = f2bf(c.y); o.z = f2bf(c.z); o.w = f2bf(c.w);
      *(ushort4*)(dst + d4 * 4) = o;
    }
  } else {
    ushort4 z = {0, 0, 0, 0};
#pragma unroll
    for (int i = 0; i < 3; ++i) *(ushort4*)(dst + (i * 64 + l) * 4) = z;
  }
#pragma unroll
  for (int off = 32; off > 0; off >>= 1) acc += __shfl_down(acc, off, 64);
  if (l == 0) {
    float wv = 0.f;
    if (s < S_ && cand_mask[(size_t)b * S_ + s] != 0) wv = acc;
    wbuf[r] = wv;
  }
}

// ---------------- k3: qm[r][c] = sum_k ctxb[r][k] * Mt[c][k]  (bf16 out) ----
// R5-proven: gload_lds both operands, BK=64 (two 32-col panels), swizzle,
// 128x128 tile, 4 waves (2x2). [R6 lesson: MFMA-frag-layout direct global
// loads are uncoalesced (stride 3072B across lanes) — never again.]
__global__ __launch_bounds__(256) void k_qm(const ushort* __restrict__ ctxb,
                                            const ushort* __restrict__ Mt,
                                            ushort* __restrict__ qm) {
  __shared__ __align__(16) ushort As[2][128 * 32];
  __shared__ __align__(16) ushort Bs[2][128 * 32];
  int bid0 = blockIdx.x;              // 0..3071
  int xcd = bid0 & 7;
  int idx = bid0 >> 3;                // 0..383
  int bm = xcd * 64 + idx / 6;        // 0..511 (bijective)
  int bn = idx % 6;
  int row0 = bm * 128, col0 = bn * 128;
  int tid = threadIdx.x;
  int w = tid >> 6, l = tid & 63;
  int wr = w >> 1, wc = w & 1;
  int src_off = SRC_OFF(l);
  int rd_off  = RD_OFF(l);

  f32x4 acc[4][4];
#pragma unroll
  for (int m = 0; m < 4; ++m)
#pragma unroll
    for (int n = 0; n < 4; ++n) acc[m][n] = (f32x4){0.f, 0.f, 0.f, 0.f};

  for (int kt = 0; kt < D_; kt += 64) {
    if (kt) __syncthreads();
#pragma unroll
    for (int h = 0; h < 2; ++h)
#pragma unroll
      for (int g = 0; g < 2; ++g) {
        int grp = w * 2 + g;
        int grow = grp * 16 + (l >> 2);
        const ushort* asrc = ctxb + (size_t)(row0 + grow) * D_ + kt + h * 32 + src_off;
        gload16(asrc, (char*)As[h] + grp * 1024);
        const ushort* bsrc = Mt + (size_t)(col0 + grow) * D_ + kt + h * 32 + src_off;
        gload16(bsrc, (char*)Bs[h] + grp * 1024);
      }
    __syncthreads();

#pragma unroll
    for (int h = 0; h < 2; ++h) {
      bf16x8 af[4], bfr[4];
#pragma unroll
      for (int m = 0; m < 4; ++m)
        af[m] = *(const bf16x8*)&As[h][(wr * 64 + m * 16 + (l & 15)) * 32 + rd_off];
#pragma unroll
      for (int n = 0; n < 4; ++n)
        bfr[n] = *(const bf16x8*)&Bs[h][(wc * 64 + n * 16 + (l & 15)) * 32 + rd_off];
#pragma unroll
      for (int m = 0; m < 4; ++m)
#pragma unroll
        for (int n = 0; n < 4; ++n)
          acc[m][n] = __builtin_amdgcn_mfma_f32_16x16x32_bf16(af[m], bfr[n], acc[m][n], 0, 0, 0);
    }
  }

  int rbase = row0 + wr * 64;
  int cbase = col0 + wc * 64;
#pragma unroll
  for (int m = 0; m < 4; ++m)
#pragma unroll
    for (int n = 0; n < 4; ++n)
#pragma unroll
      for (int i = 0; i < 4; ++i) {
        int rr = rbase + m * 16 + (l >> 4) * 4 + i;
        int cc = cbase + n * 16 + (l & 15);
        qm[(size_t)rr * D_ + cc] = f2bf(acc[m][n][i]);
      }
}

// ---------------- k4: logits -> sigmoid -> * w -> row-sum -> x --------------
// RETILED: BM=128, BN=256, BK=64, 8 waves (2 row x 4 col), 512 threads.
// Per wave per K-step: 6 gloads vs 32 MFMA (was 10:32 at BM=64).
// Same proven 2-barrier schedule + swizzle. 2 blocks per b, XCD-adjacent.
__global__ __launch_bounds__(512) void k_attn(const ushort* __restrict__ qm,
                                              const ushort* __restrict__ candb,
                                              const float* __restrict__ wbuf,
                                              const int* __restrict__ ctx_mask,
                                              float* __restrict__ xbuf) {
  __shared__ __align__(16) ushort As[2][128 * 32];   // 16 KB
  __shared__ __align__(16) ushort Bs[2][256 * 32];   // 32 KB
  __shared__ float w_lds[256];
  __shared__ float xpart[4][128];
  int bid0 = blockIdx.x;                   // 0..511
  int nb = (bid0 & 7) * 64 + (bid0 >> 3);  // bijective XCD-chunked remap
  int b = nb >> 1, lt = nb & 1;
  int row0 = lt * 128;
  int tid = threadIdx.x;
  int w = tid >> 6, l = tid & 63;
  int wr = w >> 2, wc = w & 3;             // 2x4 wave grid
  int src_off = SRC_OFF(l);
  int rd_off  = RD_OFF(l);
  if (tid < 256) w_lds[tid] = wbuf[(size_t)b * 256 + tid];

  f32x4 acc[4][4];
#pragma unroll
  for (int m = 0; m < 4; ++m)
#pragma unroll
    for (int n = 0; n < 4; ++n) acc[m][n] = (f32x4){0.f, 0.f, 0.f, 0.f};

  size_t arow = (size_t)b * 256 + row0;    // qm rows for this block
  size_t brow = (size_t)b * 256;           // candb rows (padded)

  for (int kt = 0; kt < D_; kt += 64) {
    if (kt) __syncthreads();
    // A: 128 rows -> 1 gload/wave/panel (wave w stages rows w*16..w*16+15)
#pragma unroll
    for (int h = 0; h < 2; ++h) {
      const ushort* gsrc = qm + (arow + w * 16 + (l >> 2)) * D_ + kt + h * 32 + src_off;
      gload16(gsrc, (char*)As[h] + w * 1024);
    }
    // B: 256 rows -> 2 gloads/wave/panel
#pragma unroll
    for (int h = 0; h < 2; ++h)
#pragma unroll
      for (int g = 0; g < 2; ++g) {
        int grp = w * 2 + g;
        const ushort* gsrc = candb + (brow + grp * 16 + (l >> 2)) * D_ + kt + h * 32 + src_off;
        gload16(gsrc, (char*)Bs[h] + grp * 1024);
      }
    __syncthreads();

#pragma unroll
    for (int h = 0; h < 2; ++h) {
      bf16x8 af[4], bfr[4];
#pragma unroll
      for (int m = 0; m < 4; ++m)
        af[m] = *(const bf16x8*)&As[h][(wr * 64 + m * 16 + (l & 15)) * 32 + rd_off];
#pragma unroll
      for (int n = 0; n < 4; ++n)
        bfr[n] = *(const bf16x8*)&Bs[h][(wc * 64 + n * 16 + (l & 15)) * 32 + rd_off];
#pragma unroll
      for (int m = 0; m < 4; ++m)
#pragma unroll
        for (int n = 0; n < 4; ++n)
          acc[m][n] = __builtin_amdgcn_mfma_f32_16x16x32_bf16(af[m], bfr[n], acc[m][n], 0, 0, 0);
    }
  }

  float rs[4][4];
#pragma unroll
  for (int m = 0; m < 4; ++m)
#pragma unroll
    for (int i = 0; i < 4; ++i) rs[m][i] = 0.f;

#pragma unroll
  for (int n = 0; n < 4; ++n) {
    float wcol = w_lds[wc * 64 + n * 16 + (l & 15)];
#pragma unroll
    for (int m = 0; m < 4; ++m)
#pragma unroll
      for (int i = 0; i < 4; ++i) {
        float p = 1.f / (1.f + __expf(-acc[m][n][i]));
        rs[m][i] += p * wcol;
      }
  }
#pragma unroll
  for (int m = 0; m < 4; ++m)
#pragma unroll
    for (int i = 0; i < 4; ++i) {
      float v = rs[m][i];
      v += __shfl_xor(v, 1, 64);
      v += __shfl_xor(v, 2, 64);
      v += __shfl_xor(v, 4, 64);
      v += __shfl_xor(v, 8, 64);
      rs[m][i] = v;
    }
  __syncthreads();  // all reads of Bs/As done; xpart reuse safe w.r.t. nothing, just ordering
  if ((l & 15) == 0) {
#pragma unroll
    for (int m = 0; m < 4; ++m)
#pragma unroll
      for (int i = 0; i < 4; ++i) {
        float v = rs[m][i];
        if (wc == 0) xpart[0][wr * 64 + m * 16 + (l >> 4) * 4 + i] = v;
        else if (wc == 1) xpart[1][wr * 64 + m * 16 + (l >> 4) * 4 + i] = v;
        else if (wc == 2) xpart[2][wr * 64 + m * 16 + (l >> 4) * 4 + i] = v;
        else xpart[3][wr * 64 + m * 16 + (l >> 4) * 4 + i] = v;
      }
  }
  __syncthreads();
  if (tid < 128) {
    float xs = xpart[0][tid] + xpart[1][tid] + xpart[2][tid] + xpart[3][tid];
    int gm = ctx_mask[(size_t)b * 256 + row0 + tid];
    xbuf[(size_t)b * 256 + row0 + tid] = gm ? xs : 0.f;
  }
}

// ---------------- k5: y[b] = (x[b]^T W1 + b1) W2 + b2 ----------------------
__global__ __launch_bounds__(128) void k_mlp(const float* __restrict__ xbuf,
                                             const float* __restrict__ W1,
                                             const float* __restrict__ b1,
                                             const float* __restrict__ W2,
                                             const float* __restrict__ b2,
                                             float* __restrict__ out) {
  int b = blockIdx.x, t = threadIdx.x;
  __shared__ float xl[256];
  __shared__ float hl[128];
  xl[t]       = xbuf[(size_t)b * 256 + t];
  xl[t + 128] = xbuf[(size_t)b * 256 + 128 + t];
  __syncthreads();
  float acc = b1[t];
#pragma unroll 8
  for (int ll = 0; ll < 256; ++ll) acc += xl[ll] * W1[ll * H_ + t];
  hl[t] = acc;
  __syncthreads();
  if (t < 5) {
    float y = b2[t];
#pragma unroll 8
    for (int h = 0; h < H_; ++h) y += hl[h] * W2[h * 5 + t];
    out[(size_t)b * 5 + t] = y;
  }
}

extern "C" void kernel_launch(void* const* d_in, const int* in_sizes, int n_in,
                              void* d_out, int out_size, void* d_ws, size_t ws_size,
                              hipStream_t stream) {
  const float* ctx       = (const float*)d_in[0];
  const float* cand      = (const float*)d_in[1];
  const int*   ctx_mask  = (const int*)d_in[2];
  const int*   cand_mask = (const int*)d_in[3];
  const float* WK        = (const float*)d_in[4];
  const float* WQ        = (const float*)d_in[5];
  const float* WV        = (const float*)d_in[6];
  const float* W1        = (const float*)d_in[7];
  const float* b1        = (const float*)d_in[8];
  const float* W2        = (const float*)d_in[9];
  const float* b2        = (const float*)d_in[10];
  float* out = (float*)d_out;

  char* ws = (char*)d_ws;
  size_t off = 0;
  auto alloc = [&](size_t bytes) {
    void* p = ws + off;
    off += (bytes + 255) & ~(size_t)255;
    return p;
  };
  ushort* Mt    = (ushort*)alloc((size_t)D_ * D_ * 2);            // 1.18 MB
  float*  wbuf  = (float*) alloc((size_t)B_ * SP_ * 4);           // 256 KB
  float*  xbuf  = (float*) alloc((size_t)B_ * L_ * 4);            // 256 KB
  ushort* candb = (ushort*)alloc((size_t)B_ * SP_ * D_ * 2);      // 100.7 MB
  ushort* qm    = (ushort*)alloc((size_t)B_ * L_ * D_ * 2);       // 100.7 MB
  ushort* ctxb  = (ushort*)alloc((size_t)B_ * L_ * D_ * 2);       // 100.7 MB
  (void)ws_size; (void)in_sizes; (void)n_in; (void)out_size;

  k_mt  <<<(D_ / 4) * 3,      256, 0, stream>>>(WK, WQ, Mt);
  k_ctxb<<<2048,              256, 0, stream>>>(ctx, ctxb);
  k_cand<<<(B_ * SP_) / 4,    256, 0, stream>>>(cand, cand_mask, WV, candb, wbuf);
  k_qm  <<<B_ * L_ / 128 * 6, 256, 0, stream>>>(ctxb, Mt, qm);
  k_attn<<<B_ * 2,            512, 0, stream>>>(qm, candb, wbuf, ctx_mask, xbuf);
  k_mlp <<<B_,                128, 0, stream>>>(xbuf, W1, b1, W2, b2, out);
}

// Round 8
// 336.494 us; speedup vs baseline: 1.5381x; 1.1058x over previous
//
#include <hip/hip_runtime.h>
#include <hip/hip_bf16.h>
#include <stdint.h>

#define B_  256
#define L_  256
#define S_  253
#define SP_ 256   // padded S
#define D_  768
#define H_  128

typedef __bf16 bf16x8 __attribute__((ext_vector_type(8)));
typedef float  f32x4  __attribute__((ext_vector_type(4)));

__device__ __forceinline__ ushort f2bf(float f) {
  union { float f; uint32_t u; } v; v.f = f;
  uint32_t r = v.u + 0x7FFFu + ((v.u >> 16) & 1u);  // RNE
  return (ushort)(r >> 16);
}

__device__ __forceinline__ uint32_t cvtpk(float lo, float hi) {
  uint32_t r;
  asm("v_cvt_pk_bf16_f32 %0, %1, %2" : "=v"(r) : "v"(lo), "v"(hi));
  return r;
}

__device__ __forceinline__ void gload16(const void* g, void* l) {
  __builtin_amdgcn_global_load_lds((const __attribute__((address_space(1))) void*)g,
                                   (__attribute__((address_space(3))) void*)l,
                                   16, 0, 0);
}

// Bank swizzle (verified R5: SQ_LDS_BANK_CONFLICT -> 0). LDS rows of 32 ushort
// = 4 slots of 16 B; stored slot s at row r holds global slot s ^ ((r>>1)&3).
#define SRC_OFF(l) ((((l) & 3) ^ (((l) >> 3) & 3)) * 8)
#define RD_OFF(l)  (((((l) >> 4) ^ (((l) >> 1) & 3))) * 8)

// ---------------- k0: Mt[i][j] = scale * sum_t WK[i,t] * WQ[j,t] (bf16) -----
__global__ __launch_bounds__(256) void k_mt(const float* __restrict__ WK,
                                            const float* __restrict__ WQ,
                                            ushort* __restrict__ Mt) {
  const float scale = 0.03608439182435161f;  // 1/sqrt(768)
  int bid = blockIdx.x;
  int i0 = (bid / 3) * 4;
  int j  = (bid % 3) * 256 + threadIdx.x;
  const float4* wq  = (const float4*)(WQ + (size_t)j * D_);
  const float4* wk0 = (const float4*)(WK + (size_t)(i0 + 0) * D_);
  const float4* wk1 = (const float4*)(WK + (size_t)(i0 + 1) * D_);
  const float4* wk2 = (const float4*)(WK + (size_t)(i0 + 2) * D_);
  const float4* wk3 = (const float4*)(WK + (size_t)(i0 + 3) * D_);
  float a0 = 0.f, a1 = 0.f, a2 = 0.f, a3 = 0.f;
#pragma unroll 4
  for (int t = 0; t < D_ / 4; ++t) {
    float4 q = wq[t];
    float4 k0 = wk0[t], k1 = wk1[t], k2 = wk2[t], k3 = wk3[t];
    a0 += q.x * k0.x + q.y * k0.y + q.z * k0.z + q.w * k0.w;
    a1 += q.x * k1.x + q.y * k1.y + q.z * k1.z + q.w * k1.w;
    a2 += q.x * k2.x + q.y * k2.y + q.z * k2.z + q.w * k2.w;
    a3 += q.x * k3.x + q.y * k3.y + q.z * k3.z + q.w * k3.w;
  }
  Mt[(size_t)(i0 + 0) * D_ + j] = f2bf(a0 * scale);
  Mt[(size_t)(i0 + 1) * D_ + j] = f2bf(a1 * scale);
  Mt[(size_t)(i0 + 2) * D_ + j] = f2bf(a2 * scale);
  Mt[(size_t)(i0 + 3) * D_ + j] = f2bf(a3 * scale);
}

// ---------------- k1: cand -> bf16 (padded), w[b,s] = mask * (cand . WV) ----
__global__ __launch_bounds__(256) void k_cand(const float* __restrict__ cand,
                                              const int* __restrict__ cand_mask,
                                              const float* __restrict__ WV,
                                              ushort* __restrict__ candb,
                                              float* __restrict__ wbuf) {
  int r = blockIdx.x * 4 + (threadIdx.x >> 6);  // padded row id, one wave per row
  int l = threadIdx.x & 63;
  int b = r >> 8, s = r & 255;
  float acc = 0.f;
  ushort* dst = candb + (size_t)r * D_;
  if (s < S_) {
    const float4* src = (const float4*)(cand + ((size_t)b * S_ + s) * D_);
    const float4* wv4 = (const float4*)WV;
#pragma unroll
    for (int i = 0; i < 3; ++i) {
      int d4 = i * 64 + l;
      float4 c = src[d4];
      float4 v = wv4[d4];
      acc += c.x * v.x + c.y * v.y + c.z * v.z + c.w * v.w;
      ushort4 o;
      o.x = f2bf(c.x); o.y = f2bf(c.y); o.z = f2bf(c.z); o.w = f2bf(c.w);
      *(ushort4*)(dst + d4 * 4) = o;
    }
  } else {
    ushort4 z = {0, 0, 0, 0};
#pragma unroll
    for (int i = 0; i < 3; ++i) *(ushort4*)(dst + (i * 64 + l) * 4) = z;
  }
#pragma unroll
  for (int off = 32; off > 0; off >>= 1) acc += __shfl_down(acc, off, 64);
  if (l == 0) {
    float wv = 0.f;
    if (s < S_ && cand_mask[(size_t)b * S_ + s] != 0) wv = acc;
    wbuf[r] = wv;
  }
}

// ---------------- k2: qm[r][c] = sum_k ctx[r][k] * Mt[c][k]  (bf16 out) -----
// R5 2-barrier skeleton, BUT A comes from ctx f32 directly: per kt, coalesced
// f32x4 loads are issued one iteration EARLY (reg prefetch; drained by the
// barrier's implicit vmcnt(0)), and the staging slot only does cvt_pk +
// ds_write_b64 into the same swizzled As layout. B unchanged (gload_lds).
// Kills the k_ctxb pass. [R4 lesson: never load-and-use A in one window;
// R6 lesson: frag-layout direct global loads are uncoalesced.]
__global__ __launch_bounds__(256) void k_qm(const float* __restrict__ ctx,
                                            const ushort* __restrict__ Mt,
                                            ushort* __restrict__ qm) {
  __shared__ __align__(16) ushort As[2][128 * 32];
  __shared__ __align__(16) ushort Bs[2][128 * 32];
  int bid0 = blockIdx.x;              // 0..3071
  int xcd = bid0 & 7;
  int idx = bid0 >> 3;                // 0..383
  int bm = xcd * 64 + idx / 6;        // 0..511 (bijective)
  int bn = idx % 6;
  int row0 = bm * 128, col0 = bn * 128;
  int tid = threadIdx.x;
  int w = tid >> 6, l = tid & 63;
  int wr = w >> 1, wc = w & 1;
  int src_off = SRC_OFF(l);
  int rd_off  = RD_OFF(l);

  // A staging map: chunk = j*256 + tid -> row r = j*16 + rt, f32 cols 4*c4..+3
  int rt = tid >> 4;                  // 0..15
  int c4 = tid & 15;                  // 0..15 (4-f32 chunk)
  int h_thr = c4 >> 3;                // which 32-col half
  int cw = c4 & 7;                    // chunk within half
  const float* athr = ctx + (size_t)(row0 + rt) * D_ + 4 * c4;
  // LDS write byte offset (within As[h_thr]); row term rt*64, slot swizzled.
  int aw_base = rt * 64 + ((cw >> 1) ^ ((rt >> 1) & 3)) * 16 + (cw & 1) * 8;
  char* aw_ptr = (char*)&As[h_thr][0] + aw_base;

  f32x4 acc[4][4];
#pragma unroll
  for (int m = 0; m < 4; ++m)
#pragma unroll
    for (int n = 0; n < 4; ++n) acc[m][n] = (f32x4){0.f, 0.f, 0.f, 0.f};

  // Prologue: prefetch A regs for kt=0
  float4 ap0, ap1, ap2, ap3, ap4, ap5, ap6, ap7;
  ap0 = *(const float4*)(athr + 0 * 12288);
  ap1 = *(const float4*)(athr + 1 * 12288);
  ap2 = *(const float4*)(athr + 2 * 12288);
  ap3 = *(const float4*)(athr + 3 * 12288);
  ap4 = *(const float4*)(athr + 4 * 12288);
  ap5 = *(const float4*)(athr + 5 * 12288);
  ap6 = *(const float4*)(athr + 6 * 12288);
  ap7 = *(const float4*)(athr + 7 * 12288);

  for (int i = 0; i < 12; ++i) {
    int kt = i * 64;
    if (i) __syncthreads();           // barrier-1: prev MFMA reads done
    // (a) cvt + ds_write A for THIS kt (regs arrived >= 1 barrier ago)
    {
      uint2 d;
      d.x = cvtpk(ap0.x, ap0.y); d.y = cvtpk(ap0.z, ap0.w);
      *(uint2*)(aw_ptr + 0 * 1024) = d;
      d.x = cvtpk(ap1.x, ap1.y); d.y = cvtpk(ap1.z, ap1.w);
      *(uint2*)(aw_ptr + 1 * 1024) = d;
      d.x = cvtpk(ap2.x, ap2.y); d.y = cvtpk(ap2.z, ap2.w);
      *(uint2*)(aw_ptr + 2 * 1024) = d;
      d.x = cvtpk(ap3.x, ap3.y); d.y = cvtpk(ap3.z, ap3.w);
      *(uint2*)(aw_ptr + 3 * 1024) = d;
      d.x = cvtpk(ap4.x, ap4.y); d.y = cvtpk(ap4.z, ap4.w);
      *(uint2*)(aw_ptr + 4 * 1024) = d;
      d.x = cvtpk(ap5.x, ap5.y); d.y = cvtpk(ap5.z, ap5.w);
      *(uint2*)(aw_ptr + 5 * 1024) = d;
      d.x = cvtpk(ap6.x, ap6.y); d.y = cvtpk(ap6.z, ap6.w);
      *(uint2*)(aw_ptr + 6 * 1024) = d;
      d.x = cvtpk(ap7.x, ap7.y); d.y = cvtpk(ap7.z, ap7.w);
      *(uint2*)(aw_ptr + 7 * 1024) = d;
    }
    // (b) B: async global->LDS for THIS kt (unchanged from R5/R7)
#pragma unroll
    for (int hh = 0; hh < 2; ++hh)
#pragma unroll
      for (int g = 0; g < 2; ++g) {
        int grp = w * 2 + g;
        int grow = grp * 16 + (l >> 2);
        const ushort* bsrc = Mt + (size_t)(col0 + grow) * D_ + kt + hh * 32 + src_off;
        gload16(bsrc, (char*)Bs[hh] + grp * 1024);
      }
    // (c) prefetch A regs for NEXT kt (clamped reload on last iter)
    {
      int ktn = (i < 11) ? kt + 64 : kt;
      const float* an = athr + ktn;
      ap0 = *(const float4*)(an + 0 * 12288);
      ap1 = *(const float4*)(an + 1 * 12288);
      ap2 = *(const float4*)(an + 2 * 12288);
      ap3 = *(const float4*)(an + 3 * 12288);
      ap4 = *(const float4*)(an + 4 * 12288);
      ap5 = *(const float4*)(an + 5 * 12288);
      ap6 = *(const float4*)(an + 6 * 12288);
      ap7 = *(const float4*)(an + 7 * 12288);
    }
    __syncthreads();                  // barrier-2: drains gloads + ds_writes

#pragma unroll
    for (int hh = 0; hh < 2; ++hh) {
      bf16x8 af[4], bfr[4];
#pragma unroll
      for (int m = 0; m < 4; ++m)
        af[m] = *(const bf16x8*)&As[hh][(wr * 64 + m * 16 + (l & 15)) * 32 + rd_off];
#pragma unroll
      for (int n = 0; n < 4; ++n)
        bfr[n] = *(const bf16x8*)&Bs[hh][(wc * 64 + n * 16 + (l & 15)) * 32 + rd_off];
#pragma unroll
      for (int m = 0; m < 4; ++m)
#pragma unroll
        for (int n = 0; n < 4; ++n)
          acc[m][n] = __builtin_amdgcn_mfma_f32_16x16x32_bf16(af[m], bfr[n], acc[m][n], 0, 0, 0);
    }
  }

  int rbase = row0 + wr * 64;
  int cbase = col0 + wc * 64;
#pragma unroll
  for (int m = 0; m < 4; ++m)
#pragma unroll
    for (int n = 0; n < 4; ++n)
#pragma unroll
      for (int i = 0; i < 4; ++i) {
        int rr = rbase + m * 16 + (l >> 4) * 4 + i;
        int cc = cbase + n * 16 + (l & 15);
        qm[(size_t)rr * D_ + cc] = f2bf(acc[m][n][i]);
      }
}

// ---------------- k3: logits -> sigmoid -> * w -> row-sum -> x --------------
// BM=128, BN=256, BK=64, 8 waves (2x4), 512 threads (R7, neutral vs R5).
__global__ __launch_bounds__(512) void k_attn(const ushort* __restrict__ qm,
                                              const ushort* __restrict__ candb,
                                              const float* __restrict__ wbuf,
                                              const int* __restrict__ ctx_mask,
                                              float* __restrict__ xbuf) {
  __shared__ __align__(16) ushort As[2][128 * 32];   // 16 KB
  __shared__ __align__(16) ushort Bs[2][256 * 32];   // 32 KB
  __shared__ float w_lds[256];
  __shared__ float xpart[4][128];
  int bid0 = blockIdx.x;                   // 0..511
  int nb = (bid0 & 7) * 64 + (bid0 >> 3);  // bijective XCD-chunked remap
  int b = nb >> 1, lt = nb & 1;
  int row0 = lt * 128;
  int tid = threadIdx.x;
  int w = tid >> 6, l = tid & 63;
  int wr = w >> 2, wc = w & 3;             // 2x4 wave grid
  int src_off = SRC_OFF(l);
  int rd_off  = RD_OFF(l);
  if (tid < 256) w_lds[tid] = wbuf[(size_t)b * 256 + tid];

  f32x4 acc[4][4];
#pragma unroll
  for (int m = 0; m < 4; ++m)
#pragma unroll
    for (int n = 0; n < 4; ++n) acc[m][n] = (f32x4){0.f, 0.f, 0.f, 0.f};

  size_t arow = (size_t)b * 256 + row0;    // qm rows for this block
  size_t brow = (size_t)b * 256;           // candb rows (padded)

  for (int kt = 0; kt < D_; kt += 64) {
    if (kt) __syncthreads();
#pragma unroll
    for (int h = 0; h < 2; ++h) {
      const ushort* gsrc = qm + (arow + w * 16 + (l >> 2)) * D_ + kt + h * 32 + src_off;
      gload16(gsrc, (char*)As[h] + w * 1024);
    }
#pragma unroll
    for (int h = 0; h < 2; ++h)
#pragma unroll
      for (int g = 0; g < 2; ++g) {
        int grp = w * 2 + g;
        const ushort* gsrc = candb + (brow + grp * 16 + (l >> 2)) * D_ + kt + h * 32 + src_off;
        gload16(gsrc, (char*)Bs[h] + grp * 1024);
      }
    __syncthreads();

#pragma unroll
    for (int h = 0; h < 2; ++h) {
      bf16x8 af[4], bfr[4];
#pragma unroll
      for (int m = 0; m < 4; ++m)
        af[m] = *(const bf16x8*)&As[h][(wr * 64 + m * 16 + (l & 15)) * 32 + rd_off];
#pragma unroll
      for (int n = 0; n < 4; ++n)
        bfr[n] = *(const bf16x8*)&Bs[h][(wc * 64 + n * 16 + (l & 15)) * 32 + rd_off];
#pragma unroll
      for (int m = 0; m < 4; ++m)
#pragma unroll
        for (int n = 0; n < 4; ++n)
          acc[m][n] = __builtin_amdgcn_mfma_f32_16x16x32_bf16(af[m], bfr[n], acc[m][n], 0, 0, 0);
    }
  }

  float rs[4][4];
#pragma unroll
  for (int m = 0; m < 4; ++m)
#pragma unroll
    for (int i = 0; i < 4; ++i) rs[m][i] = 0.f;

#pragma unroll
  for (int n = 0; n < 4; ++n) {
    float wcol = w_lds[wc * 64 + n * 16 + (l & 15)];
#pragma unroll
    for (int m = 0; m < 4; ++m)
#pragma unroll
      for (int i = 0; i < 4; ++i) {
        float p = 1.f / (1.f + __expf(-acc[m][n][i]));
        rs[m][i] += p * wcol;
      }
  }
#pragma unroll
  for (int m = 0; m < 4; ++m)
#pragma unroll
    for (int i = 0; i < 4; ++i) {
      float v = rs[m][i];
      v += __shfl_xor(v, 1, 64);
      v += __shfl_xor(v, 2, 64);
      v += __shfl_xor(v, 4, 64);
      v += __shfl_xor(v, 8, 64);
      rs[m][i] = v;
    }
  __syncthreads();
  if ((l & 15) == 0) {
#pragma unroll
    for (int m = 0; m < 4; ++m)
#pragma unroll
      for (int i = 0; i < 4; ++i)
        xpart[wc][wr * 64 + m * 16 + (l >> 4) * 4 + i] = rs[m][i];
  }
  __syncthreads();
  if (tid < 128) {
    float xs = xpart[0][tid] + xpart[1][tid] + xpart[2][tid] + xpart[3][tid];
    int gm = ctx_mask[(size_t)b * 256 + row0 + tid];
    xbuf[(size_t)b * 256 + row0 + tid] = gm ? xs : 0.f;
  }
}

// ---------------- k4: y[b] = (x[b]^T W1 + b1) W2 + b2 ----------------------
__global__ __launch_bounds__(128) void k_mlp(const float* __restrict__ xbuf,
                                             const float* __restrict__ W1,
                                             const float* __restrict__ b1,
                                             const float* __restrict__ W2,
                                             const float* __restrict__ b2,
                                             float* __restrict__ out) {
  int b = blockIdx.x, t = threadIdx.x;
  __shared__ float xl[256];
  __shared__ float hl[128];
  xl[t]       = xbuf[(size_t)b * 256 + t];
  xl[t + 128] = xbuf[(size_t)b * 256 + 128 + t];
  __syncthreads();
  float acc = b1[t];
#pragma unroll 8
  for (int ll = 0; ll < 256; ++ll) acc += xl[ll] * W1[ll * H_ + t];
  hl[t] = acc;
  __syncthreads();
  if (t < 5) {
    float y = b2[t];
#pragma unroll 8
    for (int h = 0; h < H_; ++h) y += hl[h] * W2[h * 5 + t];
    out[(size_t)b * 5 + t] = y;
  }
}

extern "C" void kernel_launch(void* const* d_in, const int* in_sizes, int n_in,
                              void* d_out, int out_size, void* d_ws, size_t ws_size,
                              hipStream_t stream) {
  const float* ctx       = (const float*)d_in[0];
  const float* cand      = (const float*)d_in[1];
  const int*   ctx_mask  = (const int*)d_in[2];
  const int*   cand_mask = (const int*)d_in[3];
  const float* WK        = (const float*)d_in[4];
  const float* WQ        = (const float*)d_in[5];
  const float* WV        = (const float*)d_in[6];
  const float* W1        = (const float*)d_in[7];
  const float* b1        = (const float*)d_in[8];
  const float* W2        = (const float*)d_in[9];
  const float* b2        = (const float*)d_in[10];
  float* out = (float*)d_out;

  char* ws = (char*)d_ws;
  size_t off = 0;
  auto alloc = [&](size_t bytes) {
    void* p = ws + off;
    off += (bytes + 255) & ~(size_t)255;
    return p;
  };
  ushort* Mt    = (ushort*)alloc((size_t)D_ * D_ * 2);            // 1.18 MB
  float*  wbuf  = (float*) alloc((size_t)B_ * SP_ * 4);           // 256 KB
  float*  xbuf  = (float*) alloc((size_t)B_ * L_ * 4);            // 256 KB
  ushort* candb = (ushort*)alloc((size_t)B_ * SP_ * D_ * 2);      // 100.7 MB
  ushort* qm    = (ushort*)alloc((size_t)B_ * L_ * D_ * 2);       // 100.7 MB
  (void)ws_size; (void)in_sizes; (void)n_in; (void)out_size;

  k_mt  <<<(D_ / 4) * 3,      256, 0, stream>>>(WK, WQ, Mt);
  k_cand<<<(B_ * SP_) / 4,    256, 0, stream>>>(cand, cand_mask, WV, candb, wbuf);
  k_qm  <<<B_ * L_ / 128 * 6, 256, 0, stream>>>(ctx, Mt, qm);
  k_attn<<<B_ * 2,            512, 0, stream>>>(qm, candb, wbuf, ctx_mask, xbuf);
  k_mlp <<<B_,                128, 0, stream>>>(xbuf, W1, b1, W2, b2, out);
}

// Round 9
// 277.960 us; speedup vs baseline: 1.8620x; 1.2106x over previous
//
#include <hip/hip_runtime.h>
#include <hip/hip_bf16.h>
#include <stdint.h>

#define B_  256
#define L_  256
#define S_  253
#define D_  768
#define H_  128

typedef __bf16 bf16x8 __attribute__((ext_vector_type(8)));
typedef float  f32x4  __attribute__((ext_vector_type(4)));

__device__ __forceinline__ ushort f2bf(float f) {
  union { float f; uint32_t u; } v; v.f = f;
  uint32_t r = v.u + 0x7FFFu + ((v.u >> 16) & 1u);  // RNE
  return (ushort)(r >> 16);
}

__device__ __forceinline__ uint32_t cvtpk(float lo, float hi) {
  uint32_t r;
  asm("v_cvt_pk_bf16_f32 %0, %1, %2" : "=v"(r) : "v"(lo), "v"(hi));
  return r;
}

__device__ __forceinline__ void gload16(const void* g, void* l) {
  __builtin_amdgcn_global_load_lds((const __attribute__((address_space(1))) void*)g,
                                   (__attribute__((address_space(3))) void*)l,
                                   16, 0, 0);
}

// Bank swizzle (verified R5: SQ_LDS_BANK_CONFLICT -> 0 on reads). LDS rows of
// 32 ushort = 4 slots of 16 B; stored slot s at row r holds global slot
// s ^ ((r>>1)&3). Panels padded by 32 ushorts (64 B) so panel 1 sits 16 banks
// off panel 0 -> quarter-wave writes (h=0,1) cover all 32 banks (R8 fix).
#define SRC_OFF(l) ((((l) & 3) ^ (((l) >> 3) & 3)) * 8)
#define RD_OFF(l)  (((((l) >> 4) ^ (((l) >> 1) & 3))) * 8)
#define PANEL128 (128 * 32 + 32)
#define PANEL256 (256 * 32 + 32)

// ---------------- k_wqb: WQ f32 -> bf16 row-copy ----------------------------
__global__ __launch_bounds__(256) void k_wqb(const float* __restrict__ WQ,
                                             ushort* __restrict__ wqb) {
  int i = blockIdx.x * 256 + threadIdx.x;   // 147456 float4s exactly
  float4 c = ((const float4*)WQ)[i];
  ushort4 o;
  o.x = f2bf(c.x); o.y = f2bf(c.y); o.z = f2bf(c.z); o.w = f2bf(c.w);
  ((ushort4*)wqb)[i] = o;
}

// ---------------- k_mtm: Mt[i][j] = scale * sum_t WK[i,t]*WQ[j,t] (MFMA) ----
// k_qm body at grid 36 (6x6 tiles of 768x768). A = WK f32 (reg-prefetch+cvt),
// B = wqb bf16 (gload_lds). Scale folded into epilogue.
__global__ __launch_bounds__(256) void k_mtm(const float* __restrict__ WK,
                                             const ushort* __restrict__ wqb,
                                             ushort* __restrict__ Mt) {
  const float scale = 0.03608439182435161f;  // 1/sqrt(768)
  __shared__ __align__(16) ushort As[2][PANEL128];
  __shared__ __align__(16) ushort Bs[2][PANEL128];
  int bm = blockIdx.x / 6, bn = blockIdx.x % 6;
  int row0 = bm * 128, col0 = bn * 128;
  int tid = threadIdx.x;
  int w = tid >> 6, l = tid & 63;
  int wr = w >> 1, wc = w & 1;
  int src_off = SRC_OFF(l);
  int rd_off  = RD_OFF(l);

  int rt = tid >> 4;
  int c4 = tid & 15;
  int h_thr = c4 >> 3;
  int cw = c4 & 7;
  const float* athr = WK + (size_t)(row0 + rt) * D_ + 4 * c4;
  int aw_base = rt * 64 + ((cw >> 1) ^ ((rt >> 1) & 3)) * 16 + (cw & 1) * 8;
  char* aw_ptr = (char*)&As[h_thr][0] + aw_base;

  f32x4 acc[4][4];
#pragma unroll
  for (int m = 0; m < 4; ++m)
#pragma unroll
    for (int n = 0; n < 4; ++n) acc[m][n] = (f32x4){0.f, 0.f, 0.f, 0.f};

  float4 ap0, ap1, ap2, ap3, ap4, ap5, ap6, ap7;
  ap0 = *(const float4*)(athr + 0 * 12288);
  ap1 = *(const float4*)(athr + 1 * 12288);
  ap2 = *(const float4*)(athr + 2 * 12288);
  ap3 = *(const float4*)(athr + 3 * 12288);
  ap4 = *(const float4*)(athr + 4 * 12288);
  ap5 = *(const float4*)(athr + 5 * 12288);
  ap6 = *(const float4*)(athr + 6 * 12288);
  ap7 = *(const float4*)(athr + 7 * 12288);

  for (int i = 0; i < 12; ++i) {
    int kt = i * 64;
    if (i) __syncthreads();
    {
      uint2 d;
      d.x = cvtpk(ap0.x, ap0.y); d.y = cvtpk(ap0.z, ap0.w);
      *(uint2*)(aw_ptr + 0 * 1024) = d;
      d.x = cvtpk(ap1.x, ap1.y); d.y = cvtpk(ap1.z, ap1.w);
      *(uint2*)(aw_ptr + 1 * 1024) = d;
      d.x = cvtpk(ap2.x, ap2.y); d.y = cvtpk(ap2.z, ap2.w);
      *(uint2*)(aw_ptr + 2 * 1024) = d;
      d.x = cvtpk(ap3.x, ap3.y); d.y = cvtpk(ap3.z, ap3.w);
      *(uint2*)(aw_ptr + 3 * 1024) = d;
      d.x = cvtpk(ap4.x, ap4.y); d.y = cvtpk(ap4.z, ap4.w);
      *(uint2*)(aw_ptr + 4 * 1024) = d;
      d.x = cvtpk(ap5.x, ap5.y); d.y = cvtpk(ap5.z, ap5.w);
      *(uint2*)(aw_ptr + 5 * 1024) = d;
      d.x = cvtpk(ap6.x, ap6.y); d.y = cvtpk(ap6.z, ap6.w);
      *(uint2*)(aw_ptr + 6 * 1024) = d;
      d.x = cvtpk(ap7.x, ap7.y); d.y = cvtpk(ap7.z, ap7.w);
      *(uint2*)(aw_ptr + 7 * 1024) = d;
    }
#pragma unroll
    for (int hh = 0; hh < 2; ++hh)
#pragma unroll
      for (int g = 0; g < 2; ++g) {
        int grp = w * 2 + g;
        int grow = grp * 16 + (l >> 2);
        const ushort* bsrc = wqb + (size_t)(col0 + grow) * D_ + kt + hh * 32 + src_off;
        gload16(bsrc, (char*)Bs[hh] + grp * 1024);
      }
    {
      int ktn = (i < 11) ? kt + 64 : kt;
      const float* an = athr + ktn;
      ap0 = *(const float4*)(an + 0 * 12288);
      ap1 = *(const float4*)(an + 1 * 12288);
      ap2 = *(const float4*)(an + 2 * 12288);
      ap3 = *(const float4*)(an + 3 * 12288);
      ap4 = *(const float4*)(an + 4 * 12288);
      ap5 = *(const float4*)(an + 5 * 12288);
      ap6 = *(const float4*)(an + 6 * 12288);
      ap7 = *(const float4*)(an + 7 * 12288);
    }
    __syncthreads();

#pragma unroll
    for (int hh = 0; hh < 2; ++hh) {
      bf16x8 af[4], bfr[4];
#pragma unroll
      for (int m = 0; m < 4; ++m)
        af[m] = *(const bf16x8*)&As[hh][(wr * 64 + m * 16 + (l & 15)) * 32 + rd_off];
#pragma unroll
      for (int n = 0; n < 4; ++n)
        bfr[n] = *(const bf16x8*)&Bs[hh][(wc * 64 + n * 16 + (l & 15)) * 32 + rd_off];
#pragma unroll
      for (int m = 0; m < 4; ++m)
#pragma unroll
        for (int n = 0; n < 4; ++n)
          acc[m][n] = __builtin_amdgcn_mfma_f32_16x16x32_bf16(af[m], bfr[n], acc[m][n], 0, 0, 0);
    }
  }

  int rbase = row0 + wr * 64;
  int cbase = col0 + wc * 64;
#pragma unroll
  for (int m = 0; m < 4; ++m)
#pragma unroll
    for (int n = 0; n < 4; ++n)
#pragma unroll
      for (int i = 0; i < 4; ++i) {
        int rr = rbase + m * 16 + (l >> 4) * 4 + i;
        int cc = cbase + n * 16 + (l & 15);
        Mt[(size_t)rr * D_ + cc] = f2bf(acc[m][n][i] * scale);
      }
}

// ---------------- k_qm: qm[r][c] = sum_k ctx[r][k] * Mt[c][k]  (bf16) -------
// R8 structure + panel pad (write-conflict fix).
__global__ __launch_bounds__(256) void k_qm(const float* __restrict__ ctx,
                                            const ushort* __restrict__ Mt,
                                            ushort* __restrict__ qm) {
  __shared__ __align__(16) ushort As[2][PANEL128];
  __shared__ __align__(16) ushort Bs[2][PANEL128];
  int bid0 = blockIdx.x;              // 0..3071
  int xcd = bid0 & 7;
  int idx = bid0 >> 3;                // 0..383
  int bm = xcd * 64 + idx / 6;        // 0..511 (bijective)
  int bn = idx % 6;
  int row0 = bm * 128, col0 = bn * 128;
  int tid = threadIdx.x;
  int w = tid >> 6, l = tid & 63;
  int wr = w >> 1, wc = w & 1;
  int src_off = SRC_OFF(l);
  int rd_off  = RD_OFF(l);

  int rt = tid >> 4;
  int c4 = tid & 15;
  int h_thr = c4 >> 3;
  int cw = c4 & 7;
  const float* athr = ctx + (size_t)(row0 + rt) * D_ + 4 * c4;
  int aw_base = rt * 64 + ((cw >> 1) ^ ((rt >> 1) & 3)) * 16 + (cw & 1) * 8;
  char* aw_ptr = (char*)&As[h_thr][0] + aw_base;

  f32x4 acc[4][4];
#pragma unroll
  for (int m = 0; m < 4; ++m)
#pragma unroll
    for (int n = 0; n < 4; ++n) acc[m][n] = (f32x4){0.f, 0.f, 0.f, 0.f};

  float4 ap0, ap1, ap2, ap3, ap4, ap5, ap6, ap7;
  ap0 = *(const float4*)(athr + 0 * 12288);
  ap1 = *(const float4*)(athr + 1 * 12288);
  ap2 = *(const float4*)(athr + 2 * 12288);
  ap3 = *(const float4*)(athr + 3 * 12288);
  ap4 = *(const float4*)(athr + 4 * 12288);
  ap5 = *(const float4*)(athr + 5 * 12288);
  ap6 = *(const float4*)(athr + 6 * 12288);
  ap7 = *(const float4*)(athr + 7 * 12288);

  for (int i = 0; i < 12; ++i) {
    int kt = i * 64;
    if (i) __syncthreads();
    {
      uint2 d;
      d.x = cvtpk(ap0.x, ap0.y); d.y = cvtpk(ap0.z, ap0.w);
      *(uint2*)(aw_ptr + 0 * 1024) = d;
      d.x = cvtpk(ap1.x, ap1.y); d.y = cvtpk(ap1.z, ap1.w);
      *(uint2*)(aw_ptr + 1 * 1024) = d;
      d.x = cvtpk(ap2.x, ap2.y); d.y = cvtpk(ap2.z, ap2.w);
      *(uint2*)(aw_ptr + 2 * 1024) = d;
      d.x = cvtpk(ap3.x, ap3.y); d.y = cvtpk(ap3.z, ap3.w);
      *(uint2*)(aw_ptr + 3 * 1024) = d;
      d.x = cvtpk(ap4.x, ap4.y); d.y = cvtpk(ap4.z, ap4.w);
      *(uint2*)(aw_ptr + 4 * 1024) = d;
      d.x = cvtpk(ap5.x, ap5.y); d.y = cvtpk(ap5.z, ap5.w);
      *(uint2*)(aw_ptr + 5 * 1024) = d;
      d.x = cvtpk(ap6.x, ap6.y); d.y = cvtpk(ap6.z, ap6.w);
      *(uint2*)(aw_ptr + 6 * 1024) = d;
      d.x = cvtpk(ap7.x, ap7.y); d.y = cvtpk(ap7.z, ap7.w);
      *(uint2*)(aw_ptr + 7 * 1024) = d;
    }
#pragma unroll
    for (int hh = 0; hh < 2; ++hh)
#pragma unroll
      for (int g = 0; g < 2; ++g) {
        int grp = w * 2 + g;
        int grow = grp * 16 + (l >> 2);
        const ushort* bsrc = Mt + (size_t)(col0 + grow) * D_ + kt + hh * 32 + src_off;
        gload16(bsrc, (char*)Bs[hh] + grp * 1024);
      }
    {
      int ktn = (i < 11) ? kt + 64 : kt;
      const float* an = athr + ktn;
      ap0 = *(const float4*)(an + 0 * 12288);
      ap1 = *(const float4*)(an + 1 * 12288);
      ap2 = *(const float4*)(an + 2 * 12288);
      ap3 = *(const float4*)(an + 3 * 12288);
      ap4 = *(const float4*)(an + 4 * 12288);
      ap5 = *(const float4*)(an + 5 * 12288);
      ap6 = *(const float4*)(an + 6 * 12288);
      ap7 = *(const float4*)(an + 7 * 12288);
    }
    __syncthreads();

#pragma unroll
    for (int hh = 0; hh < 2; ++hh) {
      bf16x8 af[4], bfr[4];
#pragma unroll
      for (int m = 0; m < 4; ++m)
        af[m] = *(const bf16x8*)&As[hh][(wr * 64 + m * 16 + (l & 15)) * 32 + rd_off];
#pragma unroll
      for (int n = 0; n < 4; ++n)
        bfr[n] = *(const bf16x8*)&Bs[hh][(wc * 64 + n * 16 + (l & 15)) * 32 + rd_off];
#pragma unroll
      for (int m = 0; m < 4; ++m)
#pragma unroll
        for (int n = 0; n < 4; ++n)
          acc[m][n] = __builtin_amdgcn_mfma_f32_16x16x32_bf16(af[m], bfr[n], acc[m][n], 0, 0, 0);
    }
  }

  int rbase = row0 + wr * 64;
  int cbase = col0 + wc * 64;
#pragma unroll
  for (int m = 0; m < 4; ++m)
#pragma unroll
    for (int n = 0; n < 4; ++n)
#pragma unroll
      for (int i = 0; i < 4; ++i) {
        int rr = rbase + m * 16 + (l >> 4) * 4 + i;
        int cc = cbase + n * 16 + (l & 15);
        qm[(size_t)rr * D_ + cc] = f2bf(acc[m][n][i]);
      }
}

// ---------------- k_attn: full fusion -------------------------------------
// BM=256 (one block per b), BN=256, BK=64, 1024 thr, 16 waves (4x4).
// A (qm bf16): gload_lds. B (cand f32): reg-prefetch -> cvt_pk -> swizzled
// ds_write (R8-proven pattern); rows >= 253 zeroed. w = (cand.WV)*mask fused:
// per-thread partials + 16-lane shfl reduce -> w_lds. Kills k_cand/candb/wbuf.
__global__ __launch_bounds__(1024) void k_attn(const ushort* __restrict__ qm,
                                               const float* __restrict__ cand,
                                               const int* __restrict__ cand_mask,
                                               const int* __restrict__ ctx_mask,
                                               const float* __restrict__ WV,
                                               float* __restrict__ xbuf) {
  __shared__ __align__(16) ushort As[2][PANEL256];
  __shared__ __align__(16) ushort Bs[2][PANEL256];
  __shared__ float wv_lds[D_];
  __shared__ float w_lds[256];
  __shared__ float xpart[4][256];
  int b = blockIdx.x;
  int tid = threadIdx.x;
  int w = tid >> 6, l = tid & 63;
  int wr = w >> 2, wc = w & 3;             // 4x4 wave grid
  int src_off = SRC_OFF(l);
  int rd_off  = RD_OFF(l);

  if (tid < D_) wv_lds[tid] = WV[tid];

  // B staging map: rt = tid>>4 (0..63), rows rt+64k (k=0..3), cols 4*c4..+3
  int rt = tid >> 4;
  int c4 = tid & 15;
  int h_thr = c4 >> 3;
  int cw = c4 & 7;
  int row_k0 = rt, row_k1 = rt + 64, row_k2 = rt + 128, row_k3 = rt + 192;
  int ok3 = row_k3 < S_;                   // only k=3 can be out of range
  const float* bptr0 = cand + ((size_t)b * S_ + row_k0) * D_ + 4 * c4;
  const float* bptr1 = cand + ((size_t)b * S_ + row_k1) * D_ + 4 * c4;
  const float* bptr2 = cand + ((size_t)b * S_ + row_k2) * D_ + 4 * c4;
  const float* bptr3 = cand + ((size_t)b * S_ + (ok3 ? row_k3 : S_ - 1)) * D_ + 4 * c4;
  int bw_base = rt * 64 + ((cw >> 1) ^ ((rt >> 1) & 3)) * 16 + (cw & 1) * 8;
  char* bw_ptr = (char*)&Bs[h_thr][0] + bw_base;

  f32x4 acc[4][4];
#pragma unroll
  for (int m = 0; m < 4; ++m)
#pragma unroll
    for (int n = 0; n < 4; ++n) acc[m][n] = (f32x4){0.f, 0.f, 0.f, 0.f};
  float wa0 = 0.f, wa1 = 0.f, wa2 = 0.f, wa3 = 0.f;

  size_t arow = (size_t)b * 256;
  __syncthreads();  // wv_lds ready

  float4 bp0 = *(const float4*)(bptr0);
  float4 bp1 = *(const float4*)(bptr1);
  float4 bp2 = *(const float4*)(bptr2);
  float4 bp3 = *(const float4*)(bptr3);
  if (!ok3) bp3 = (float4){0.f, 0.f, 0.f, 0.f};

  for (int i = 0; i < 12; ++i) {
    int kt = i * 64;
    if (i) __syncthreads();
    // (a) cvt + ds_write B for THIS kt
    {
      uint2 d;
      d.x = cvtpk(bp0.x, bp0.y); d.y = cvtpk(bp0.z, bp0.w);
      *(uint2*)(bw_ptr + 0 * 4096) = d;
      d.x = cvtpk(bp1.x, bp1.y); d.y = cvtpk(bp1.z, bp1.w);
      *(uint2*)(bw_ptr + 1 * 4096) = d;
      d.x = cvtpk(bp2.x, bp2.y); d.y = cvtpk(bp2.z, bp2.w);
      *(uint2*)(bw_ptr + 2 * 4096) = d;
      d.x = cvtpk(bp3.x, bp3.y); d.y = cvtpk(bp3.z, bp3.w);
      *(uint2*)(bw_ptr + 3 * 4096) = d;
    }
    // (b) A: qm bf16 via gload_lds (wave w -> rows w*16..+15 per panel)
#pragma unroll
    for (int h = 0; h < 2; ++h) {
      const ushort* gsrc = qm + (arow + w * 16 + (l >> 2)) * D_ + kt + h * 32 + src_off;
      gload16(gsrc, (char*)As[h] + w * 1024);
    }
    // (c) wacc partial dots for THIS kt (uses bp before overwrite)
    {
      float4 wv = *(const float4*)&wv_lds[kt + 4 * c4];
      wa0 += bp0.x * wv.x + bp0.y * wv.y + bp0.z * wv.z + bp0.w * wv.w;
      wa1 += bp1.x * wv.x + bp1.y * wv.y + bp1.z * wv.z + bp1.w * wv.w;
      wa2 += bp2.x * wv.x + bp2.y * wv.y + bp2.z * wv.z + bp2.w * wv.w;
      wa3 += bp3.x * wv.x + bp3.y * wv.y + bp3.z * wv.z + bp3.w * wv.w;
    }
    // (d) prefetch B regs for NEXT kt
    {
      int ktn = (i < 11) ? kt + 64 : kt;
      bp0 = *(const float4*)(bptr0 + ktn);
      bp1 = *(const float4*)(bptr1 + ktn);
      bp2 = *(const float4*)(bptr2 + ktn);
      bp3 = *(const float4*)(bptr3 + ktn);
      if (!ok3) bp3 = (float4){0.f, 0.f, 0.f, 0.f};
    }
    __syncthreads();

#pragma unroll
    for (int h = 0; h < 2; ++h) {
      bf16x8 af[4], bfr[4];
#pragma unroll
      for (int m = 0; m < 4; ++m)
        af[m] = *(const bf16x8*)&As[h][(wr * 64 + m * 16 + (l & 15)) * 32 + rd_off];
#pragma unroll
      for (int n = 0; n < 4; ++n)
        bfr[n] = *(const bf16x8*)&Bs[h][(wc * 64 + n * 16 + (l & 15)) * 32 + rd_off];
#pragma unroll
      for (int m = 0; m < 4; ++m)
#pragma unroll
        for (int n = 0; n < 4; ++n)
          acc[m][n] = __builtin_amdgcn_mfma_f32_16x16x32_bf16(af[m], bfr[n], acc[m][n], 0, 0, 0);
    }
  }

  // finish w: 16-lane (c4) shfl reduce, then mask & publish
  wa0 += __shfl_xor(wa0, 1, 64); wa0 += __shfl_xor(wa0, 2, 64);
  wa0 += __shfl_xor(wa0, 4, 64); wa0 += __shfl_xor(wa0, 8, 64);
  wa1 += __shfl_xor(wa1, 1, 64); wa1 += __shfl_xor(wa1, 2, 64);
  wa1 += __shfl_xor(wa1, 4, 64); wa1 += __shfl_xor(wa1, 8, 64);
  wa2 += __shfl_xor(wa2, 1, 64); wa2 += __shfl_xor(wa2, 2, 64);
  wa2 += __shfl_xor(wa2, 4, 64); wa2 += __shfl_xor(wa2, 8, 64);
  wa3 += __shfl_xor(wa3, 1, 64); wa3 += __shfl_xor(wa3, 2, 64);
  wa3 += __shfl_xor(wa3, 4, 64); wa3 += __shfl_xor(wa3, 8, 64);
  if (c4 == 0) {
    const int* cm = cand_mask + (size_t)b * S_;
    w_lds[row_k0] = (cm[row_k0] != 0) ? wa0 : 0.f;
    w_lds[row_k1] = (cm[row_k1] != 0) ? wa1 : 0.f;
    w_lds[row_k2] = (cm[row_k2] != 0) ? wa2 : 0.f;
    w_lds[row_k3] = (ok3 && cm[ok3 ? row_k3 : 0] != 0) ? wa3 : 0.f;
  }
  __syncthreads();

  float rs[4][4];
#pragma unroll
  for (int m = 0; m < 4; ++m)
#pragma unroll
    for (int i = 0; i < 4; ++i) rs[m][i] = 0.f;

#pragma unroll
  for (int n = 0; n < 4; ++n) {
    float wcol = w_lds[wc * 64 + n * 16 + (l & 15)];
#pragma unroll
    for (int m = 0; m < 4; ++m)
#pragma unroll
      for (int i = 0; i < 4; ++i) {
        float p = 1.f / (1.f + __expf(-acc[m][n][i]));
        rs[m][i] += p * wcol;
      }
  }
#pragma unroll
  for (int m = 0; m < 4; ++m)
#pragma unroll
    for (int i = 0; i < 4; ++i) {
      float v = rs[m][i];
      v += __shfl_xor(v, 1, 64);
      v += __shfl_xor(v, 2, 64);
      v += __shfl_xor(v, 4, 64);
      v += __shfl_xor(v, 8, 64);
      rs[m][i] = v;
    }
  if ((l & 15) == 0) {
#pragma unroll
    for (int m = 0; m < 4; ++m)
#pragma unroll
      for (int i = 0; i < 4; ++i)
        xpart[wc][wr * 64 + m * 16 + (l >> 4) * 4 + i] = rs[m][i];
  }
  __syncthreads();
  if (tid < 256) {
    float xs = xpart[0][tid] + xpart[1][tid] + xpart[2][tid] + xpart[3][tid];
    int gm = ctx_mask[(size_t)b * 256 + tid];
    xbuf[(size_t)b * 256 + tid] = gm ? xs : 0.f;
  }
}

// ---------------- k_mlp: y[b] = (x[b]^T W1 + b1) W2 + b2 -------------------
__global__ __launch_bounds__(128) void k_mlp(const float* __restrict__ xbuf,
                                             const float* __restrict__ W1,
                                             const float* __restrict__ b1,
                                             const float* __restrict__ W2,
                                             const float* __restrict__ b2,
                                             float* __restrict__ out) {
  int b = blockIdx.x, t = threadIdx.x;
  __shared__ float xl[256];
  __shared__ float hl[128];
  xl[t]       = xbuf[(size_t)b * 256 + t];
  xl[t + 128] = xbuf[(size_t)b * 256 + 128 + t];
  __syncthreads();
  float acc = b1[t];
#pragma unroll 8
  for (int ll = 0; ll < 256; ++ll) acc += xl[ll] * W1[ll * H_ + t];
  hl[t] = acc;
  __syncthreads();
  if (t < 5) {
    float y = b2[t];
#pragma unroll 8
    for (int h = 0; h < H_; ++h) y += hl[h] * W2[h * 5 + t];
    out[(size_t)b * 5 + t] = y;
  }
}

extern "C" void kernel_launch(void* const* d_in, const int* in_sizes, int n_in,
                              void* d_out, int out_size, void* d_ws, size_t ws_size,
                              hipStream_t stream) {
  const float* ctx       = (const float*)d_in[0];
  const float* cand      = (const float*)d_in[1];
  const int*   ctx_mask  = (const int*)d_in[2];
  const int*   cand_mask = (const int*)d_in[3];
  const float* WK        = (const float*)d_in[4];
  const float* WQ        = (const float*)d_in[5];
  const float* WV        = (const float*)d_in[6];
  const float* W1        = (const float*)d_in[7];
  const float* b1        = (const float*)d_in[8];
  const float* W2        = (const float*)d_in[9];
  const float* b2        = (const float*)d_in[10];
  float* out = (float*)d_out;

  char* ws = (char*)d_ws;
  size_t off = 0;
  auto alloc = [&](size_t bytes) {
    void* p = ws + off;
    off += (bytes + 255) & ~(size_t)255;
    return p;
  };
  ushort* Mt   = (ushort*)alloc((size_t)D_ * D_ * 2);        // 1.18 MB
  ushort* wqb  = (ushort*)alloc((size_t)D_ * D_ * 2);        // 1.18 MB
  float*  xbuf = (float*) alloc((size_t)B_ * L_ * 4);        // 256 KB
  ushort* qm   = (ushort*)alloc((size_t)B_ * L_ * D_ * 2);   // 100.7 MB
  (void)ws_size; (void)in_sizes; (void)n_in; (void)out_size;

  k_wqb <<<D_ * D_ / 4 / 256,  256, 0, stream>>>(WQ, wqb);
  k_mtm <<<36,                 256, 0, stream>>>(WK, wqb, Mt);
  k_qm  <<<B_ * L_ / 128 * 6,  256, 0, stream>>>(ctx, Mt, qm);
  k_attn<<<B_,                1024, 0, stream>>>(qm, cand, cand_mask, ctx_mask, WV, xbuf);
  k_mlp <<<B_,                 128, 0, stream>>>(xbuf, W1, b1, W2, b2, out);
}

// Round 10
// 276.818 us; speedup vs baseline: 1.8697x; 1.0041x over previous
//
#include <hip/hip_runtime.h>
#include <hip/hip_bf16.h>
#include <stdint.h>

#define B_  256
#define L_  256
#define S_  253
#define D_  768
#define H_  128

typedef __bf16 bf16x8 __attribute__((ext_vector_type(8)));
typedef float  f32x4  __attribute__((ext_vector_type(4)));

__device__ __forceinline__ ushort f2bf(float f) {
  union { float f; uint32_t u; } v; v.f = f;
  uint32_t r = v.u + 0x7FFFu + ((v.u >> 16) & 1u);  // RNE
  return (ushort)(r >> 16);
}

__device__ __forceinline__ uint32_t cvtpk(float lo, float hi) {
  uint32_t r;
  asm("v_cvt_pk_bf16_f32 %0, %1, %2" : "=v"(r) : "v"(lo), "v"(hi));
  return r;
}

__device__ __forceinline__ void gload16(const void* g, void* l) {
  __builtin_amdgcn_global_load_lds((const __attribute__((address_space(1))) void*)g,
                                   (__attribute__((address_space(3))) void*)l,
                                   16, 0, 0);
}

// Bank swizzle (verified R5: SQ_LDS_BANK_CONFLICT -> 0 on reads). LDS rows of
// 32 ushort = 4 slots of 16 B; stored slot s at row r holds global slot
// s ^ ((r>>1)&3). Panels padded by 32 ushorts (64 B) so panel 1 sits 16 banks
// off panel 0 -> quarter-wave writes (h=0,1) cover all 32 banks (R8 fix).
#define SRC_OFF(l) ((((l) & 3) ^ (((l) >> 3) & 3)) * 8)
#define RD_OFF(l)  (((((l) >> 4) ^ (((l) >> 1) & 3))) * 8)
#define PANEL128 (128 * 32 + 32)
#define PANEL256 (256 * 32 + 32)

// ---------------- k_wqb: WQ f32 -> bf16 row-copy ----------------------------
__global__ __launch_bounds__(256) void k_wqb(const float* __restrict__ WQ,
                                             ushort* __restrict__ wqb) {
  int i = blockIdx.x * 256 + threadIdx.x;   // 147456 float4s exactly
  float4 c = ((const float4*)WQ)[i];
  ushort4 o;
  o.x = f2bf(c.x); o.y = f2bf(c.y); o.z = f2bf(c.z); o.w = f2bf(c.w);
  ((ushort4*)wqb)[i] = o;
}

// ---------------- k_mtm: Mt[i][j] = scale * sum_t WK[i,t]*WQ[j,t] (MFMA) ----
// k_qm body at grid 36 (6x6 tiles of 768x768). A = WK f32 (reg-prefetch+cvt),
// B = wqb bf16 (gload_lds). Scale folded into epilogue.
__global__ __launch_bounds__(256) void k_mtm(const float* __restrict__ WK,
                                             const ushort* __restrict__ wqb,
                                             ushort* __restrict__ Mt) {
  const float scale = 0.03608439182435161f;  // 1/sqrt(768)
  __shared__ __align__(16) ushort As[2][PANEL128];
  __shared__ __align__(16) ushort Bs[2][PANEL128];
  int bm = blockIdx.x / 6, bn = blockIdx.x % 6;
  int row0 = bm * 128, col0 = bn * 128;
  int tid = threadIdx.x;
  int w = tid >> 6, l = tid & 63;
  int wr = w >> 1, wc = w & 1;
  int src_off = SRC_OFF(l);
  int rd_off  = RD_OFF(l);

  int rt = tid >> 4;
  int c4 = tid & 15;
  int h_thr = c4 >> 3;
  int cw = c4 & 7;
  const float* athr = WK + (size_t)(row0 + rt) * D_ + 4 * c4;
  int aw_base = rt * 64 + ((cw >> 1) ^ ((rt >> 1) & 3)) * 16 + (cw & 1) * 8;
  char* aw_ptr = (char*)&As[h_thr][0] + aw_base;

  f32x4 acc[4][4];
#pragma unroll
  for (int m = 0; m < 4; ++m)
#pragma unroll
    for (int n = 0; n < 4; ++n) acc[m][n] = (f32x4){0.f, 0.f, 0.f, 0.f};

  float4 ap0, ap1, ap2, ap3, ap4, ap5, ap6, ap7;
  ap0 = *(const float4*)(athr + 0 * 12288);
  ap1 = *(const float4*)(athr + 1 * 12288);
  ap2 = *(const float4*)(athr + 2 * 12288);
  ap3 = *(const float4*)(athr + 3 * 12288);
  ap4 = *(const float4*)(athr + 4 * 12288);
  ap5 = *(const float4*)(athr + 5 * 12288);
  ap6 = *(const float4*)(athr + 6 * 12288);
  ap7 = *(const float4*)(athr + 7 * 12288);

  for (int i = 0; i < 12; ++i) {
    int kt = i * 64;
    if (i) __syncthreads();
    {
      uint2 d;
      d.x = cvtpk(ap0.x, ap0.y); d.y = cvtpk(ap0.z, ap0.w);
      *(uint2*)(aw_ptr + 0 * 1024) = d;
      d.x = cvtpk(ap1.x, ap1.y); d.y = cvtpk(ap1.z, ap1.w);
      *(uint2*)(aw_ptr + 1 * 1024) = d;
      d.x = cvtpk(ap2.x, ap2.y); d.y = cvtpk(ap2.z, ap2.w);
      *(uint2*)(aw_ptr + 2 * 1024) = d;
      d.x = cvtpk(ap3.x, ap3.y); d.y = cvtpk(ap3.z, ap3.w);
      *(uint2*)(aw_ptr + 3 * 1024) = d;
      d.x = cvtpk(ap4.x, ap4.y); d.y = cvtpk(ap4.z, ap4.w);
      *(uint2*)(aw_ptr + 4 * 1024) = d;
      d.x = cvtpk(ap5.x, ap5.y); d.y = cvtpk(ap5.z, ap5.w);
      *(uint2*)(aw_ptr + 5 * 1024) = d;
      d.x = cvtpk(ap6.x, ap6.y); d.y = cvtpk(ap6.z, ap6.w);
      *(uint2*)(aw_ptr + 6 * 1024) = d;
      d.x = cvtpk(ap7.x, ap7.y); d.y = cvtpk(ap7.z, ap7.w);
      *(uint2*)(aw_ptr + 7 * 1024) = d;
    }
#pragma unroll
    for (int hh = 0; hh < 2; ++hh)
#pragma unroll
      for (int g = 0; g < 2; ++g) {
        int grp = w * 2 + g;
        int grow = grp * 16 + (l >> 2);
        const ushort* bsrc = wqb + (size_t)(col0 + grow) * D_ + kt + hh * 32 + src_off;
        gload16(bsrc, (char*)Bs[hh] + grp * 1024);
      }
    {
      int ktn = (i < 11) ? kt + 64 : kt;
      const float* an = athr + ktn;
      ap0 = *(const float4*)(an + 0 * 12288);
      ap1 = *(const float4*)(an + 1 * 12288);
      ap2 = *(const float4*)(an + 2 * 12288);
      ap3 = *(const float4*)(an + 3 * 12288);
      ap4 = *(const float4*)(an + 4 * 12288);
      ap5 = *(const float4*)(an + 5 * 12288);
      ap6 = *(const float4*)(an + 6 * 12288);
      ap7 = *(const float4*)(an + 7 * 12288);
    }
    __syncthreads();

#pragma unroll
    for (int hh = 0; hh < 2; ++hh) {
      bf16x8 af[4], bfr[4];
#pragma unroll
      for (int m = 0; m < 4; ++m)
        af[m] = *(const bf16x8*)&As[hh][(wr * 64 + m * 16 + (l & 15)) * 32 + rd_off];
#pragma unroll
      for (int n = 0; n < 4; ++n)
        bfr[n] = *(const bf16x8*)&Bs[hh][(wc * 64 + n * 16 + (l & 15)) * 32 + rd_off];
#pragma unroll
      for (int m = 0; m < 4; ++m)
#pragma unroll
        for (int n = 0; n < 4; ++n)
          acc[m][n] = __builtin_amdgcn_mfma_f32_16x16x32_bf16(af[m], bfr[n], acc[m][n], 0, 0, 0);
    }
  }

  int rbase = row0 + wr * 64;
  int cbase = col0 + wc * 64;
#pragma unroll
  for (int m = 0; m < 4; ++m)
#pragma unroll
    for (int n = 0; n < 4; ++n)
#pragma unroll
      for (int i = 0; i < 4; ++i) {
        int rr = rbase + m * 16 + (l >> 4) * 4 + i;
        int cc = cbase + n * 16 + (l & 15);
        Mt[(size_t)rr * D_ + cc] = f2bf(acc[m][n][i] * scale);
      }
}

// ---------------- k_qm: qm[r][c] = sum_k ctx[r][k] * Mt[c][k]  (bf16) -------
// R8 structure + panel pad (write-conflict fix).
__global__ __launch_bounds__(256) void k_qm(const float* __restrict__ ctx,
                                            const ushort* __restrict__ Mt,
                                            ushort* __restrict__ qm) {
  __shared__ __align__(16) ushort As[2][PANEL128];
  __shared__ __align__(16) ushort Bs[2][PANEL128];
  int bid0 = blockIdx.x;              // 0..3071
  int xcd = bid0 & 7;
  int idx = bid0 >> 3;                // 0..383
  int bm = xcd * 64 + idx / 6;        // 0..511 (bijective)
  int bn = idx % 6;
  int row0 = bm * 128, col0 = bn * 128;
  int tid = threadIdx.x;
  int w = tid >> 6, l = tid & 63;
  int wr = w >> 1, wc = w & 1;
  int src_off = SRC_OFF(l);
  int rd_off  = RD_OFF(l);

  int rt = tid >> 4;
  int c4 = tid & 15;
  int h_thr = c4 >> 3;
  int cw = c4 & 7;
  const float* athr = ctx + (size_t)(row0 + rt) * D_ + 4 * c4;
  int aw_base = rt * 64 + ((cw >> 1) ^ ((rt >> 1) & 3)) * 16 + (cw & 1) * 8;
  char* aw_ptr = (char*)&As[h_thr][0] + aw_base;

  f32x4 acc[4][4];
#pragma unroll
  for (int m = 0; m < 4; ++m)
#pragma unroll
    for (int n = 0; n < 4; ++n) acc[m][n] = (f32x4){0.f, 0.f, 0.f, 0.f};

  float4 ap0, ap1, ap2, ap3, ap4, ap5, ap6, ap7;
  ap0 = *(const float4*)(athr + 0 * 12288);
  ap1 = *(const float4*)(athr + 1 * 12288);
  ap2 = *(const float4*)(athr + 2 * 12288);
  ap3 = *(const float4*)(athr + 3 * 12288);
  ap4 = *(const float4*)(athr + 4 * 12288);
  ap5 = *(const float4*)(athr + 5 * 12288);
  ap6 = *(const float4*)(athr + 6 * 12288);
  ap7 = *(const float4*)(athr + 7 * 12288);

  for (int i = 0; i < 12; ++i) {
    int kt = i * 64;
    if (i) __syncthreads();
    {
      uint2 d;
      d.x = cvtpk(ap0.x, ap0.y); d.y = cvtpk(ap0.z, ap0.w);
      *(uint2*)(aw_ptr + 0 * 1024) = d;
      d.x = cvtpk(ap1.x, ap1.y); d.y = cvtpk(ap1.z, ap1.w);
      *(uint2*)(aw_ptr + 1 * 1024) = d;
      d.x = cvtpk(ap2.x, ap2.y); d.y = cvtpk(ap2.z, ap2.w);
      *(uint2*)(aw_ptr + 2 * 1024) = d;
      d.x = cvtpk(ap3.x, ap3.y); d.y = cvtpk(ap3.z, ap3.w);
      *(uint2*)(aw_ptr + 3 * 1024) = d;
      d.x = cvtpk(ap4.x, ap4.y); d.y = cvtpk(ap4.z, ap4.w);
      *(uint2*)(aw_ptr + 4 * 1024) = d;
      d.x = cvtpk(ap5.x, ap5.y); d.y = cvtpk(ap5.z, ap5.w);
      *(uint2*)(aw_ptr + 5 * 1024) = d;
      d.x = cvtpk(ap6.x, ap6.y); d.y = cvtpk(ap6.z, ap6.w);
      *(uint2*)(aw_ptr + 6 * 1024) = d;
      d.x = cvtpk(ap7.x, ap7.y); d.y = cvtpk(ap7.z, ap7.w);
      *(uint2*)(aw_ptr + 7 * 1024) = d;
    }
#pragma unroll
    for (int hh = 0; hh < 2; ++hh)
#pragma unroll
      for (int g = 0; g < 2; ++g) {
        int grp = w * 2 + g;
        int grow = grp * 16 + (l >> 2);
        const ushort* bsrc = Mt + (size_t)(col0 + grow) * D_ + kt + hh * 32 + src_off;
        gload16(bsrc, (char*)Bs[hh] + grp * 1024);
      }
    {
      int ktn = (i < 11) ? kt + 64 : kt;
      const float* an = athr + ktn;
      ap0 = *(const float4*)(an + 0 * 12288);
      ap1 = *(const float4*)(an + 1 * 12288);
      ap2 = *(const float4*)(an + 2 * 12288);
      ap3 = *(const float4*)(an + 3 * 12288);
      ap4 = *(const float4*)(an + 4 * 12288);
      ap5 = *(const float4*)(an + 5 * 12288);
      ap6 = *(const float4*)(an + 6 * 12288);
      ap7 = *(const float4*)(an + 7 * 12288);
    }
    __syncthreads();

#pragma unroll
    for (int hh = 0; hh < 2; ++hh) {
      bf16x8 af[4], bfr[4];
#pragma unroll
      for (int m = 0; m < 4; ++m)
        af[m] = *(const bf16x8*)&As[hh][(wr * 64 + m * 16 + (l & 15)) * 32 + rd_off];
#pragma unroll
      for (int n = 0; n < 4; ++n)
        bfr[n] = *(const bf16x8*)&Bs[hh][(wc * 64 + n * 16 + (l & 15)) * 32 + rd_off];
#pragma unroll
      for (int m = 0; m < 4; ++m)
#pragma unroll
        for (int n = 0; n < 4; ++n)
          acc[m][n] = __builtin_amdgcn_mfma_f32_16x16x32_bf16(af[m], bfr[n], acc[m][n], 0, 0, 0);
    }
  }

  int rbase = row0 + wr * 64;
  int cbase = col0 + wc * 64;
#pragma unroll
  for (int m = 0; m < 4; ++m)
#pragma unroll
    for (int n = 0; n < 4; ++n)
#pragma unroll
      for (int i = 0; i < 4; ++i) {
        int rr = rbase + m * 16 + (l >> 4) * 4 + i;
        int cc = cbase + n * 16 + (l & 15);
        qm[(size_t)rr * D_ + cc] = f2bf(acc[m][n][i]);
      }
}

// ---------------- k_attn: full fusion -------------------------------------
// BM=256 (one block per b), BN=256, BK=64, 1024 thr, 16 waves (4x4).
// A (qm bf16): gload_lds. B (cand f32): reg-prefetch -> cvt_pk -> swizzled
// ds_write (R8-proven pattern); rows >= 253 zeroed. w = (cand.WV)*mask fused:
// per-thread partials + 16-lane shfl reduce -> w_lds. Kills k_cand/candb/wbuf.
__global__ __launch_bounds__(1024) void k_attn(const ushort* __restrict__ qm,
                                               const float* __restrict__ cand,
                                               const int* __restrict__ cand_mask,
                                               const int* __restrict__ ctx_mask,
                                               const float* __restrict__ WV,
                                               float* __restrict__ xbuf) {
  __shared__ __align__(16) ushort As[2][PANEL256];
  __shared__ __align__(16) ushort Bs[2][PANEL256];
  __shared__ float wv_lds[D_];
  __shared__ float w_lds[256];
  __shared__ float xpart[4][256];
  int b = blockIdx.x;
  int tid = threadIdx.x;
  int w = tid >> 6, l = tid & 63;
  int wr = w >> 2, wc = w & 3;             // 4x4 wave grid
  int src_off = SRC_OFF(l);
  int rd_off  = RD_OFF(l);

  if (tid < D_) wv_lds[tid] = WV[tid];

  // B staging map: rt = tid>>4 (0..63), rows rt+64k (k=0..3), cols 4*c4..+3
  int rt = tid >> 4;
  int c4 = tid & 15;
  int h_thr = c4 >> 3;
  int cw = c4 & 7;
  int row_k0 = rt, row_k1 = rt + 64, row_k2 = rt + 128, row_k3 = rt + 192;
  int ok3 = row_k3 < S_;                   // only k=3 can be out of range
  const float* bptr0 = cand + ((size_t)b * S_ + row_k0) * D_ + 4 * c4;
  const float* bptr1 = cand + ((size_t)b * S_ + row_k1) * D_ + 4 * c4;
  const float* bptr2 = cand + ((size_t)b * S_ + row_k2) * D_ + 4 * c4;
  const float* bptr3 = cand + ((size_t)b * S_ + (ok3 ? row_k3 : S_ - 1)) * D_ + 4 * c4;
  int bw_base = rt * 64 + ((cw >> 1) ^ ((rt >> 1) & 3)) * 16 + (cw & 1) * 8;
  char* bw_ptr = (char*)&Bs[h_thr][0] + bw_base;

  f32x4 acc[4][4];
#pragma unroll
  for (int m = 0; m < 4; ++m)
#pragma unroll
    for (int n = 0; n < 4; ++n) acc[m][n] = (f32x4){0.f, 0.f, 0.f, 0.f};
  float wa0 = 0.f, wa1 = 0.f, wa2 = 0.f, wa3 = 0.f;

  size_t arow = (size_t)b * 256;
  __syncthreads();  // wv_lds ready

  float4 bp0 = *(const float4*)(bptr0);
  float4 bp1 = *(const float4*)(bptr1);
  float4 bp2 = *(const float4*)(bptr2);
  float4 bp3 = *(const float4*)(bptr3);
  if (!ok3) bp3 = (float4){0.f, 0.f, 0.f, 0.f};

  for (int i = 0; i < 12; ++i) {
    int kt = i * 64;
    if (i) __syncthreads();
    // (a) cvt + ds_write B for THIS kt
    {
      uint2 d;
      d.x = cvtpk(bp0.x, bp0.y); d.y = cvtpk(bp0.z, bp0.w);
      *(uint2*)(bw_ptr + 0 * 4096) = d;
      d.x = cvtpk(bp1.x, bp1.y); d.y = cvtpk(bp1.z, bp1.w);
      *(uint2*)(bw_ptr + 1 * 4096) = d;
      d.x = cvtpk(bp2.x, bp2.y); d.y = cvtpk(bp2.z, bp2.w);
      *(uint2*)(bw_ptr + 2 * 4096) = d;
      d.x = cvtpk(bp3.x, bp3.y); d.y = cvtpk(bp3.z, bp3.w);
      *(uint2*)(bw_ptr + 3 * 4096) = d;
    }
    // (b) A: qm bf16 via gload_lds (wave w -> rows w*16..+15 per panel)
#pragma unroll
    for (int h = 0; h < 2; ++h) {
      const ushort* gsrc = qm + (arow + w * 16 + (l >> 2)) * D_ + kt + h * 32 + src_off;
      gload16(gsrc, (char*)As[h] + w * 1024);
    }
    // (c) wacc partial dots for THIS kt (uses bp before overwrite)
    {
      float4 wv = *(const float4*)&wv_lds[kt + 4 * c4];
      wa0 += bp0.x * wv.x + bp0.y * wv.y + bp0.z * wv.z + bp0.w * wv.w;
      wa1 += bp1.x * wv.x + bp1.y * wv.y + bp1.z * wv.z + bp1.w * wv.w;
      wa2 += bp2.x * wv.x + bp2.y * wv.y + bp2.z * wv.z + bp2.w * wv.w;
      wa3 += bp3.x * wv.x + bp3.y * wv.y + bp3.z * wv.z + bp3.w * wv.w;
    }
    // (d) prefetch B regs for NEXT kt
    {
      int ktn = (i < 11) ? kt + 64 : kt;
      bp0 = *(const float4*)(bptr0 + ktn);
      bp1 = *(const float4*)(bptr1 + ktn);
      bp2 = *(const float4*)(bptr2 + ktn);
      bp3 = *(const float4*)(bptr3 + ktn);
      if (!ok3) bp3 = (float4){0.f, 0.f, 0.f, 0.f};
    }
    __syncthreads();

#pragma unroll
    for (int h = 0; h < 2; ++h) {
      bf16x8 af[4], bfr[4];
#pragma unroll
      for (int m = 0; m < 4; ++m)
        af[m] = *(const bf16x8*)&As[h][(wr * 64 + m * 16 + (l & 15)) * 32 + rd_off];
#pragma unroll
      for (int n = 0; n < 4; ++n)
        bfr[n] = *(const bf16x8*)&Bs[h][(wc * 64 + n * 16 + (l & 15)) * 32 + rd_off];
#pragma unroll
      for (int m = 0; m < 4; ++m)
#pragma unroll
        for (int n = 0; n < 4; ++n)
          acc[m][n] = __builtin_amdgcn_mfma_f32_16x16x32_bf16(af[m], bfr[n], acc[m][n], 0, 0, 0);
    }
  }

  // finish w: 16-lane (c4) shfl reduce, then mask & publish
  wa0 += __shfl_xor(wa0, 1, 64); wa0 += __shfl_xor(wa0, 2, 64);
  wa0 += __shfl_xor(wa0, 4, 64); wa0 += __shfl_xor(wa0, 8, 64);
  wa1 += __shfl_xor(wa1, 1, 64); wa1 += __shfl_xor(wa1, 2, 64);
  wa1 += __shfl_xor(wa1, 4, 64); wa1 += __shfl_xor(wa1, 8, 64);
  wa2 += __shfl_xor(wa2, 1, 64); wa2 += __shfl_xor(wa2, 2, 64);
  wa2 += __shfl_xor(wa2, 4, 64); wa2 += __shfl_xor(wa2, 8, 64);
  wa3 += __shfl_xor(wa3, 1, 64); wa3 += __shfl_xor(wa3, 2, 64);
  wa3 += __shfl_xor(wa3, 4, 64); wa3 += __shfl_xor(wa3, 8, 64);
  if (c4 == 0) {
    const int* cm = cand_mask + (size_t)b * S_;
    w_lds[row_k0] = (cm[row_k0] != 0) ? wa0 : 0.f;
    w_lds[row_k1] = (cm[row_k1] != 0) ? wa1 : 0.f;
    w_lds[row_k2] = (cm[row_k2] != 0) ? wa2 : 0.f;
    w_lds[row_k3] = (ok3 && cm[ok3 ? row_k3 : 0] != 0) ? wa3 : 0.f;
  }
  __syncthreads();

  float rs[4][4];
#pragma unroll
  for (int m = 0; m < 4; ++m)
#pragma unroll
    for (int i = 0; i < 4; ++i) rs[m][i] = 0.f;

#pragma unroll
  for (int n = 0; n < 4; ++n) {
    float wcol = w_lds[wc * 64 + n * 16 + (l & 15)];
#pragma unroll
    for (int m = 0; m < 4; ++m)
#pragma unroll
      for (int i = 0; i < 4; ++i) {
        float p = 1.f / (1.f + __expf(-acc[m][n][i]));
        rs[m][i] += p * wcol;
      }
  }
#pragma unroll
  for (int m = 0; m < 4; ++m)
#pragma unroll
    for (int i = 0; i < 4; ++i) {
      float v = rs[m][i];
      v += __shfl_xor(v, 1, 64);
      v += __shfl_xor(v, 2, 64);
      v += __shfl_xor(v, 4, 64);
      v += __shfl_xor(v, 8, 64);
      rs[m][i] = v;
    }
  if ((l & 15) == 0) {
#pragma unroll
    for (int m = 0; m < 4; ++m)
#pragma unroll
      for (int i = 0; i < 4; ++i)
        xpart[wc][wr * 64 + m * 16 + (l >> 4) * 4 + i] = rs[m][i];
  }
  __syncthreads();
  if (tid < 256) {
    float xs = xpart[0][tid] + xpart[1][tid] + xpart[2][tid] + xpart[3][tid];
    int gm = ctx_mask[(size_t)b * 256 + tid];
    xbuf[(size_t)b * 256 + tid] = gm ? xs : 0.f;
  }
}

// ---------------- k_mlp: y[b] = (x[b]^T W1 + b1) W2 + b2 -------------------
__global__ __launch_bounds__(128) void k_mlp(const float* __restrict__ xbuf,
                                             const float* __restrict__ W1,
                                             const float* __restrict__ b1,
                                             const float* __restrict__ W2,
                                             const float* __restrict__ b2,
                                             float* __restrict__ out) {
  int b = blockIdx.x, t = threadIdx.x;
  __shared__ float xl[256];
  __shared__ float hl[128];
  xl[t]       = xbuf[(size_t)b * 256 + t];
  xl[t + 128] = xbuf[(size_t)b * 256 + 128 + t];
  __syncthreads();
  float acc = b1[t];
#pragma unroll 8
  for (int ll = 0; ll < 256; ++ll) acc += xl[ll] * W1[ll * H_ + t];
  hl[t] = acc;
  __syncthreads();
  if (t < 5) {
    float y = b2[t];
#pragma unroll 8
    for (int h = 0; h < H_; ++h) y += hl[h] * W2[h * 5 + t];
    out[(size_t)b * 5 + t] = y;
  }
}

extern "C" void kernel_launch(void* const* d_in, const int* in_sizes, int n_in,
                              void* d_out, int out_size, void* d_ws, size_t ws_size,
                              hipStream_t stream) {
  const float* ctx       = (const float*)d_in[0];
  const float* cand      = (const float*)d_in[1];
  const int*   ctx_mask  = (const int*)d_in[2];
  const int*   cand_mask = (const int*)d_in[3];
  const float* WK        = (const float*)d_in[4];
  const float* WQ        = (const float*)d_in[5];
  const float* WV        = (const float*)d_in[6];
  const float* W1        = (const float*)d_in[7];
  const float* b1        = (const float*)d_in[8];
  const float* W2        = (const float*)d_in[9];
  const float* b2        = (const float*)d_in[10];
  float* out = (float*)d_out;

  char* ws = (char*)d_ws;
  size_t off = 0;
  auto alloc = [&](size_t bytes) {
    void* p = ws + off;
    off += (bytes + 255) & ~(size_t)255;
    return p;
  };
  ushort* Mt   = (ushort*)alloc((size_t)D_ * D_ * 2);        // 1.18 MB
  ushort* wqb  = (ushort*)alloc((size_t)D_ * D_ * 2);        // 1.18 MB
  float*  xbuf = (float*) alloc((size_t)B_ * L_ * 4);        // 256 KB
  ushort* qm   = (ushort*)alloc((size_t)B_ * L_ * D_ * 2);   // 100.7 MB
  (void)ws_size; (void)in_sizes; (void)n_in; (void)out_size;

  k_wqb <<<D_ * D_ / 4 / 256,  256, 0, stream>>>(WQ, wqb);
  k_mtm <<<36,                 256, 0, stream>>>(WK, wqb, Mt);
  k_qm  <<<B_ * L_ / 128 * 6,  256, 0, stream>>>(ctx, Mt, qm);
  k_attn<<<B_,                1024, 0, stream>>>(qm, cand, cand_mask, ctx_mask, WV, xbuf);
  k_mlp <<<B_,                 128, 0, stream>>>(xbuf, W1, b1, W2, b2, out);
}

// Round 11
// 276.032 us; speedup vs baseline: 1.8750x; 1.0028x over previous
//
#include <hip/hip_runtime.h>
#include <hip/hip_bf16.h>
#include <stdint.h>

#define B_  256
#define L_  256
#define S_  253
#define D_  768
#define H_  128

typedef __bf16 bf16x8 __attribute__((ext_vector_type(8)));
typedef float  f32x4  __attribute__((ext_vector_type(4)));

__device__ __forceinline__ ushort f2bf(float f) {
  union { float f; uint32_t u; } v; v.f = f;
  uint32_t r = v.u + 0x7FFFu + ((v.u >> 16) & 1u);  // RNE
  return (ushort)(r >> 16);
}

__device__ __forceinline__ uint32_t cvtpk(float lo, float hi) {
  uint32_t r;
  asm("v_cvt_pk_bf16_f32 %0, %1, %2" : "=v"(r) : "v"(lo), "v"(hi));
  return r;
}

__device__ __forceinline__ void gload16(const void* g, void* l) {
  __builtin_amdgcn_global_load_lds((const __attribute__((address_space(1))) void*)g,
                                   (__attribute__((address_space(3))) void*)l,
                                   16, 0, 0);
}

// Bank swizzle (verified R5: read conflicts -> 0). LDS rows of 32 ushort =
// 4 slots of 16 B; stored slot s at row r holds global slot s ^ ((r>>1)&3).
// PANELS UNPADDED (R10 lesson): 2x16KB panels keep k_qm at LDS=32768 ->
// 5 blocks/CU; the +64B pad cost a resident block (-20 us) to fix only a
// benign 2-way WRITE alias. k_attn's PANEL256 keeps pad (grid-limited occ).
#define SRC_OFF(l) ((((l) & 3) ^ (((l) >> 3) & 3)) * 8)
#define RD_OFF(l)  (((((l) >> 4) ^ (((l) >> 1) & 3))) * 8)
#define PANEL128 (128 * 32)
#define PANEL256 (256 * 32 + 32)

// ---------------- k_wqb: WQ f32 -> bf16 row-copy ----------------------------
__global__ __launch_bounds__(256) void k_wqb(const float* __restrict__ WQ,
                                             ushort* __restrict__ wqb) {
  int i = blockIdx.x * 256 + threadIdx.x;   // 147456 float4s exactly
  float4 c = ((const float4*)WQ)[i];
  ushort4 o;
  o.x = f2bf(c.x); o.y = f2bf(c.y); o.z = f2bf(c.z); o.w = f2bf(c.w);
  ((ushort4*)wqb)[i] = o;
}

// ---------------- k_mtm: Mt[i][j] = scale * sum_t WK[i,t]*WQ[j,t] (MFMA) ----
__global__ __launch_bounds__(256) void k_mtm(const float* __restrict__ WK,
                                             const ushort* __restrict__ wqb,
                                             ushort* __restrict__ Mt) {
  const float scale = 0.03608439182435161f;  // 1/sqrt(768)
  __shared__ __align__(16) ushort As[2][PANEL128];
  __shared__ __align__(16) ushort Bs[2][PANEL128];
  int bm = blockIdx.x / 6, bn = blockIdx.x % 6;
  int row0 = bm * 128, col0 = bn * 128;
  int tid = threadIdx.x;
  int w = tid >> 6, l = tid & 63;
  int wr = w >> 1, wc = w & 1;
  int src_off = SRC_OFF(l);
  int rd_off  = RD_OFF(l);

  int rt = tid >> 4;
  int c4 = tid & 15;
  int h_thr = c4 >> 3;
  int cw = c4 & 7;
  const float* athr = WK + (size_t)(row0 + rt) * D_ + 4 * c4;
  int aw_base = rt * 64 + ((cw >> 1) ^ ((rt >> 1) & 3)) * 16 + (cw & 1) * 8;
  char* aw_ptr = (char*)&As[h_thr][0] + aw_base;

  f32x4 acc[4][4];
#pragma unroll
  for (int m = 0; m < 4; ++m)
#pragma unroll
    for (int n = 0; n < 4; ++n) acc[m][n] = (f32x4){0.f, 0.f, 0.f, 0.f};

  float4 ap0, ap1, ap2, ap3, ap4, ap5, ap6, ap7;
  ap0 = *(const float4*)(athr + 0 * 12288);
  ap1 = *(const float4*)(athr + 1 * 12288);
  ap2 = *(const float4*)(athr + 2 * 12288);
  ap3 = *(const float4*)(athr + 3 * 12288);
  ap4 = *(const float4*)(athr + 4 * 12288);
  ap5 = *(const float4*)(athr + 5 * 12288);
  ap6 = *(const float4*)(athr + 6 * 12288);
  ap7 = *(const float4*)(athr + 7 * 12288);

  for (int i = 0; i < 12; ++i) {
    int kt = i * 64;
    if (i) __syncthreads();
    {
      uint2 d;
      d.x = cvtpk(ap0.x, ap0.y); d.y = cvtpk(ap0.z, ap0.w);
      *(uint2*)(aw_ptr + 0 * 1024) = d;
      d.x = cvtpk(ap1.x, ap1.y); d.y = cvtpk(ap1.z, ap1.w);
      *(uint2*)(aw_ptr + 1 * 1024) = d;
      d.x = cvtpk(ap2.x, ap2.y); d.y = cvtpk(ap2.z, ap2.w);
      *(uint2*)(aw_ptr + 2 * 1024) = d;
      d.x = cvtpk(ap3.x, ap3.y); d.y = cvtpk(ap3.z, ap3.w);
      *(uint2*)(aw_ptr + 3 * 1024) = d;
      d.x = cvtpk(ap4.x, ap4.y); d.y = cvtpk(ap4.z, ap4.w);
      *(uint2*)(aw_ptr + 4 * 1024) = d;
      d.x = cvtpk(ap5.x, ap5.y); d.y = cvtpk(ap5.z, ap5.w);
      *(uint2*)(aw_ptr + 5 * 1024) = d;
      d.x = cvtpk(ap6.x, ap6.y); d.y = cvtpk(ap6.z, ap6.w);
      *(uint2*)(aw_ptr + 6 * 1024) = d;
      d.x = cvtpk(ap7.x, ap7.y); d.y = cvtpk(ap7.z, ap7.w);
      *(uint2*)(aw_ptr + 7 * 1024) = d;
    }
#pragma unroll
    for (int hh = 0; hh < 2; ++hh)
#pragma unroll
      for (int g = 0; g < 2; ++g) {
        int grp = w * 2 + g;
        int grow = grp * 16 + (l >> 2);
        const ushort* bsrc = wqb + (size_t)(col0 + grow) * D_ + kt + hh * 32 + src_off;
        gload16(bsrc, (char*)Bs[hh] + grp * 1024);
      }
    {
      int ktn = (i < 11) ? kt + 64 : kt;
      const float* an = athr + ktn;
      ap0 = *(const float4*)(an + 0 * 12288);
      ap1 = *(const float4*)(an + 1 * 12288);
      ap2 = *(const float4*)(an + 2 * 12288);
      ap3 = *(const float4*)(an + 3 * 12288);
      ap4 = *(const float4*)(an + 4 * 12288);
      ap5 = *(const float4*)(an + 5 * 12288);
      ap6 = *(const float4*)(an + 6 * 12288);
      ap7 = *(const float4*)(an + 7 * 12288);
    }
    __syncthreads();

#pragma unroll
    for (int hh = 0; hh < 2; ++hh) {
      bf16x8 af[4], bfr[4];
#pragma unroll
      for (int m = 0; m < 4; ++m)
        af[m] = *(const bf16x8*)&As[hh][(wr * 64 + m * 16 + (l & 15)) * 32 + rd_off];
#pragma unroll
      for (int n = 0; n < 4; ++n)
        bfr[n] = *(const bf16x8*)&Bs[hh][(wc * 64 + n * 16 + (l & 15)) * 32 + rd_off];
#pragma unroll
      for (int m = 0; m < 4; ++m)
#pragma unroll
        for (int n = 0; n < 4; ++n)
          acc[m][n] = __builtin_amdgcn_mfma_f32_16x16x32_bf16(af[m], bfr[n], acc[m][n], 0, 0, 0);
    }
  }

  int rbase = row0 + wr * 64;
  int cbase = col0 + wc * 64;
#pragma unroll
  for (int m = 0; m < 4; ++m)
#pragma unroll
    for (int n = 0; n < 4; ++n)
#pragma unroll
      for (int i = 0; i < 4; ++i) {
        int rr = rbase + m * 16 + (l >> 4) * 4 + i;
        int cc = cbase + n * 16 + (l & 15);
        Mt[(size_t)rr * D_ + cc] = f2bf(acc[m][n][i] * scale);
      }
}

// ---------------- k_qm: qm[r][c] = sum_k ctx[r][k] * Mt[c][k]  (bf16) -------
// Exact R8 structure (unpadded panels, LDS=32768).
__global__ __launch_bounds__(256) void k_qm(const float* __restrict__ ctx,
                                            const ushort* __restrict__ Mt,
                                            ushort* __restrict__ qm) {
  __shared__ __align__(16) ushort As[2][PANEL128];
  __shared__ __align__(16) ushort Bs[2][PANEL128];
  int bid0 = blockIdx.x;              // 0..3071
  int xcd = bid0 & 7;
  int idx = bid0 >> 3;                // 0..383
  int bm = xcd * 64 + idx / 6;        // 0..511 (bijective)
  int bn = idx % 6;
  int row0 = bm * 128, col0 = bn * 128;
  int tid = threadIdx.x;
  int w = tid >> 6, l = tid & 63;
  int wr = w >> 1, wc = w & 1;
  int src_off = SRC_OFF(l);
  int rd_off  = RD_OFF(l);

  int rt = tid >> 4;
  int c4 = tid & 15;
  int h_thr = c4 >> 3;
  int cw = c4 & 7;
  const float* athr = ctx + (size_t)(row0 + rt) * D_ + 4 * c4;
  int aw_base = rt * 64 + ((cw >> 1) ^ ((rt >> 1) & 3)) * 16 + (cw & 1) * 8;
  char* aw_ptr = (char*)&As[h_thr][0] + aw_base;

  f32x4 acc[4][4];
#pragma unroll
  for (int m = 0; m < 4; ++m)
#pragma unroll
    for (int n = 0; n < 4; ++n) acc[m][n] = (f32x4){0.f, 0.f, 0.f, 0.f};

  float4 ap0, ap1, ap2, ap3, ap4, ap5, ap6, ap7;
  ap0 = *(const float4*)(athr + 0 * 12288);
  ap1 = *(const float4*)(athr + 1 * 12288);
  ap2 = *(const float4*)(athr + 2 * 12288);
  ap3 = *(const float4*)(athr + 3 * 12288);
  ap4 = *(const float4*)(athr + 4 * 12288);
  ap5 = *(const float4*)(athr + 5 * 12288);
  ap6 = *(const float4*)(athr + 6 * 12288);
  ap7 = *(const float4*)(athr + 7 * 12288);

  for (int i = 0; i < 12; ++i) {
    int kt = i * 64;
    if (i) __syncthreads();
    {
      uint2 d;
      d.x = cvtpk(ap0.x, ap0.y); d.y = cvtpk(ap0.z, ap0.w);
      *(uint2*)(aw_ptr + 0 * 1024) = d;
      d.x = cvtpk(ap1.x, ap1.y); d.y = cvtpk(ap1.z, ap1.w);
      *(uint2*)(aw_ptr + 1 * 1024) = d;
      d.x = cvtpk(ap2.x, ap2.y); d.y = cvtpk(ap2.z, ap2.w);
      *(uint2*)(aw_ptr + 2 * 1024) = d;
      d.x = cvtpk(ap3.x, ap3.y); d.y = cvtpk(ap3.z, ap3.w);
      *(uint2*)(aw_ptr + 3 * 1024) = d;
      d.x = cvtpk(ap4.x, ap4.y); d.y = cvtpk(ap4.z, ap4.w);
      *(uint2*)(aw_ptr + 4 * 1024) = d;
      d.x = cvtpk(ap5.x, ap5.y); d.y = cvtpk(ap5.z, ap5.w);
      *(uint2*)(aw_ptr + 5 * 1024) = d;
      d.x = cvtpk(ap6.x, ap6.y); d.y = cvtpk(ap6.z, ap6.w);
      *(uint2*)(aw_ptr + 6 * 1024) = d;
      d.x = cvtpk(ap7.x, ap7.y); d.y = cvtpk(ap7.z, ap7.w);
      *(uint2*)(aw_ptr + 7 * 1024) = d;
    }
#pragma unroll
    for (int hh = 0; hh < 2; ++hh)
#pragma unroll
      for (int g = 0; g < 2; ++g) {
        int grp = w * 2 + g;
        int grow = grp * 16 + (l >> 2);
        const ushort* bsrc = Mt + (size_t)(col0 + grow) * D_ + kt + hh * 32 + src_off;
        gload16(bsrc, (char*)Bs[hh] + grp * 1024);
      }
    {
      int ktn = (i < 11) ? kt + 64 : kt;
      const float* an = athr + ktn;
      ap0 = *(const float4*)(an + 0 * 12288);
      ap1 = *(const float4*)(an + 1 * 12288);
      ap2 = *(const float4*)(an + 2 * 12288);
      ap3 = *(const float4*)(an + 3 * 12288);
      ap4 = *(const float4*)(an + 4 * 12288);
      ap5 = *(const float4*)(an + 5 * 12288);
      ap6 = *(const float4*)(an + 6 * 12288);
      ap7 = *(const float4*)(an + 7 * 12288);
    }
    __syncthreads();

#pragma unroll
    for (int hh = 0; hh < 2; ++hh) {
      bf16x8 af[4], bfr[4];
#pragma unroll
      for (int m = 0; m < 4; ++m)
        af[m] = *(const bf16x8*)&As[hh][(wr * 64 + m * 16 + (l & 15)) * 32 + rd_off];
#pragma unroll
      for (int n = 0; n < 4; ++n)
        bfr[n] = *(const bf16x8*)&Bs[hh][(wc * 64 + n * 16 + (l & 15)) * 32 + rd_off];
#pragma unroll
      for (int m = 0; m < 4; ++m)
#pragma unroll
        for (int n = 0; n < 4; ++n)
          acc[m][n] = __builtin_amdgcn_mfma_f32_16x16x32_bf16(af[m], bfr[n], acc[m][n], 0, 0, 0);
    }
  }

  int rbase = row0 + wr * 64;
  int cbase = col0 + wc * 64;
#pragma unroll
  for (int m = 0; m < 4; ++m)
#pragma unroll
    for (int n = 0; n < 4; ++n)
#pragma unroll
      for (int i = 0; i < 4; ++i) {
        int rr = rbase + m * 16 + (l >> 4) * 4 + i;
        int cc = cbase + n * 16 + (l & 15);
        qm[(size_t)rr * D_ + cc] = f2bf(acc[m][n][i]);
      }
}

// ---------------- k_attn: full fusion (unchanged from R9) -------------------
__global__ __launch_bounds__(1024) void k_attn(const ushort* __restrict__ qm,
                                               const float* __restrict__ cand,
                                               const int* __restrict__ cand_mask,
                                               const int* __restrict__ ctx_mask,
                                               const float* __restrict__ WV,
                                               float* __restrict__ xbuf) {
  __shared__ __align__(16) ushort As[2][PANEL256];
  __shared__ __align__(16) ushort Bs[2][PANEL256];
  __shared__ float wv_lds[D_];
  __shared__ float w_lds[256];
  __shared__ float xpart[4][256];
  int b = blockIdx.x;
  int tid = threadIdx.x;
  int w = tid >> 6, l = tid & 63;
  int wr = w >> 2, wc = w & 3;             // 4x4 wave grid
  int src_off = SRC_OFF(l);
  int rd_off  = RD_OFF(l);

  if (tid < D_) wv_lds[tid] = WV[tid];

  int rt = tid >> 4;
  int c4 = tid & 15;
  int h_thr = c4 >> 3;
  int cw = c4 & 7;
  int row_k0 = rt, row_k1 = rt + 64, row_k2 = rt + 128, row_k3 = rt + 192;
  int ok3 = row_k3 < S_;                   // only k=3 can be out of range
  const float* bptr0 = cand + ((size_t)b * S_ + row_k0) * D_ + 4 * c4;
  const float* bptr1 = cand + ((size_t)b * S_ + row_k1) * D_ + 4 * c4;
  const float* bptr2 = cand + ((size_t)b * S_ + row_k2) * D_ + 4 * c4;
  const float* bptr3 = cand + ((size_t)b * S_ + (ok3 ? row_k3 : S_ - 1)) * D_ + 4 * c4;
  int bw_base = rt * 64 + ((cw >> 1) ^ ((rt >> 1) & 3)) * 16 + (cw & 1) * 8;
  char* bw_ptr = (char*)&Bs[h_thr][0] + bw_base;

  f32x4 acc[4][4];
#pragma unroll
  for (int m = 0; m < 4; ++m)
#pragma unroll
    for (int n = 0; n < 4; ++n) acc[m][n] = (f32x4){0.f, 0.f, 0.f, 0.f};
  float wa0 = 0.f, wa1 = 0.f, wa2 = 0.f, wa3 = 0.f;

  size_t arow = (size_t)b * 256;
  __syncthreads();  // wv_lds ready

  float4 bp0 = *(const float4*)(bptr0);
  float4 bp1 = *(const float4*)(bptr1);
  float4 bp2 = *(const float4*)(bptr2);
  float4 bp3 = *(const float4*)(bptr3);
  if (!ok3) bp3 = (float4){0.f, 0.f, 0.f, 0.f};

  for (int i = 0; i < 12; ++i) {
    int kt = i * 64;
    if (i) __syncthreads();
    // (a) cvt + ds_write B for THIS kt
    {
      uint2 d;
      d.x = cvtpk(bp0.x, bp0.y); d.y = cvtpk(bp0.z, bp0.w);
      *(uint2*)(bw_ptr + 0 * 4096) = d;
      d.x = cvtpk(bp1.x, bp1.y); d.y = cvtpk(bp1.z, bp1.w);
      *(uint2*)(bw_ptr + 1 * 4096) = d;
      d.x = cvtpk(bp2.x, bp2.y); d.y = cvtpk(bp2.z, bp2.w);
      *(uint2*)(bw_ptr + 2 * 4096) = d;
      d.x = cvtpk(bp3.x, bp3.y); d.y = cvtpk(bp3.z, bp3.w);
      *(uint2*)(bw_ptr + 3 * 4096) = d;
    }
    // (b) A: qm bf16 via gload_lds
#pragma unroll
    for (int h = 0; h < 2; ++h) {
      const ushort* gsrc = qm + (arow + w * 16 + (l >> 2)) * D_ + kt + h * 32 + src_off;
      gload16(gsrc, (char*)As[h] + w * 1024);
    }
    // (c) wacc partial dots for THIS kt
    {
      float4 wv = *(const float4*)&wv_lds[kt + 4 * c4];
      wa0 += bp0.x * wv.x + bp0.y * wv.y + bp0.z * wv.z + bp0.w * wv.w;
      wa1 += bp1.x * wv.x + bp1.y * wv.y + bp1.z * wv.z + bp1.w * wv.w;
      wa2 += bp2.x * wv.x + bp2.y * wv.y + bp2.z * wv.z + bp2.w * wv.w;
      wa3 += bp3.x * wv.x + bp3.y * wv.y + bp3.z * wv.z + bp3.w * wv.w;
    }
    // (d) prefetch B regs for NEXT kt
    {
      int ktn = (i < 11) ? kt + 64 : kt;
      bp0 = *(const float4*)(bptr0 + ktn);
      bp1 = *(const float4*)(bptr1 + ktn);
      bp2 = *(const float4*)(bptr2 + ktn);
      bp3 = *(const float4*)(bptr3 + ktn);
      if (!ok3) bp3 = (float4){0.f, 0.f, 0.f, 0.f};
    }
    __syncthreads();

#pragma unroll
    for (int h = 0; h < 2; ++h) {
      bf16x8 af[4], bfr[4];
#pragma unroll
      for (int m = 0; m < 4; ++m)
        af[m] = *(const bf16x8*)&As[h][(wr * 64 + m * 16 + (l & 15)) * 32 + rd_off];
#pragma unroll
      for (int n = 0; n < 4; ++n)
        bfr[n] = *(const bf16x8*)&Bs[h][(wc * 64 + n * 16 + (l & 15)) * 32 + rd_off];
#pragma unroll
      for (int m = 0; m < 4; ++m)
#pragma unroll
        for (int n = 0; n < 4; ++n)
          acc[m][n] = __builtin_amdgcn_mfma_f32_16x16x32_bf16(af[m], bfr[n], acc[m][n], 0, 0, 0);
    }
  }

  // finish w: 16-lane (c4) shfl reduce, then mask & publish
  wa0 += __shfl_xor(wa0, 1, 64); wa0 += __shfl_xor(wa0, 2, 64);
  wa0 += __shfl_xor(wa0, 4, 64); wa0 += __shfl_xor(wa0, 8, 64);
  wa1 += __shfl_xor(wa1, 1, 64); wa1 += __shfl_xor(wa1, 2, 64);
  wa1 += __shfl_xor(wa1, 4, 64); wa1 += __shfl_xor(wa1, 8, 64);
  wa2 += __shfl_xor(wa2, 1, 64); wa2 += __shfl_xor(wa2, 2, 64);
  wa2 += __shfl_xor(wa2, 4, 64); wa2 += __shfl_xor(wa2, 8, 64);
  wa3 += __shfl_xor(wa3, 1, 64); wa3 += __shfl_xor(wa3, 2, 64);
  wa3 += __shfl_xor(wa3, 4, 64); wa3 += __shfl_xor(wa3, 8, 64);
  if (c4 == 0) {
    const int* cm = cand_mask + (size_t)b * S_;
    w_lds[row_k0] = (cm[row_k0] != 0) ? wa0 : 0.f;
    w_lds[row_k1] = (cm[row_k1] != 0) ? wa1 : 0.f;
    w_lds[row_k2] = (cm[row_k2] != 0) ? wa2 : 0.f;
    w_lds[row_k3] = (ok3 && cm[ok3 ? row_k3 : 0] != 0) ? wa3 : 0.f;
  }
  __syncthreads();

  float rs[4][4];
#pragma unroll
  for (int m = 0; m < 4; ++m)
#pragma unroll
    for (int i = 0; i < 4; ++i) rs[m][i] = 0.f;

#pragma unroll
  for (int n = 0; n < 4; ++n) {
    float wcol = w_lds[wc * 64 + n * 16 + (l & 15)];
#pragma unroll
    for (int m = 0; m < 4; ++m)
#pragma unroll
      for (int i = 0; i < 4; ++i) {
        float p = 1.f / (1.f + __expf(-acc[m][n][i]));
        rs[m][i] += p * wcol;
      }
  }
#pragma unroll
  for (int m = 0; m < 4; ++m)
#pragma unroll
    for (int i = 0; i < 4; ++i) {
      float v = rs[m][i];
      v += __shfl_xor(v, 1, 64);
      v += __shfl_xor(v, 2, 64);
      v += __shfl_xor(v, 4, 64);
      v += __shfl_xor(v, 8, 64);
      rs[m][i] = v;
    }
  if ((l & 15) == 0) {
#pragma unroll
    for (int m = 0; m < 4; ++m)
#pragma unroll
      for (int i = 0; i < 4; ++i)
        xpart[wc][wr * 64 + m * 16 + (l >> 4) * 4 + i] = rs[m][i];
  }
  __syncthreads();
  if (tid < 256) {
    float xs = xpart[0][tid] + xpart[1][tid] + xpart[2][tid] + xpart[3][tid];
    int gm = ctx_mask[(size_t)b * 256 + tid];
    xbuf[(size_t)b * 256 + tid] = gm ? xs : 0.f;
  }
}

// ---------------- k_mlp: y[b] = (x[b]^T W1 + b1) W2 + b2 -------------------
__global__ __launch_bounds__(128) void k_mlp(const float* __restrict__ xbuf,
                                             const float* __restrict__ W1,
                                             const float* __restrict__ b1,
                                             const float* __restrict__ W2,
                                             const float* __restrict__ b2,
                                             float* __restrict__ out) {
  int b = blockIdx.x, t = threadIdx.x;
  __shared__ float xl[256];
  __shared__ float hl[128];
  xl[t]       = xbuf[(size_t)b * 256 + t];
  xl[t + 128] = xbuf[(size_t)b * 256 + 128 + t];
  __syncthreads();
  float acc = b1[t];
#pragma unroll 8
  for (int ll = 0; ll < 256; ++ll) acc += xl[ll] * W1[ll * H_ + t];
  hl[t] = acc;
  __syncthreads();
  if (t < 5) {
    float y = b2[t];
#pragma unroll 8
    for (int h = 0; h < H_; ++h) y += hl[h] * W2[h * 5 + t];
    out[(size_t)b * 5 + t] = y;
  }
}

extern "C" void kernel_launch(void* const* d_in, const int* in_sizes, int n_in,
                              void* d_out, int out_size, void* d_ws, size_t ws_size,
                              hipStream_t stream) {
  const float* ctx       = (const float*)d_in[0];
  const float* cand      = (const float*)d_in[1];
  const int*   ctx_mask  = (const int*)d_in[2];
  const int*   cand_mask = (const int*)d_in[3];
  const float* WK        = (const float*)d_in[4];
  const float* WQ        = (const float*)d_in[5];
  const float* WV        = (const float*)d_in[6];
  const float* W1        = (const float*)d_in[7];
  const float* b1        = (const float*)d_in[8];
  const float* W2        = (const float*)d_in[9];
  const float* b2        = (const float*)d_in[10];
  float* out = (float*)d_out;

  char* ws = (char*)d_ws;
  size_t off = 0;
  auto alloc = [&](size_t bytes) {
    void* p = ws + off;
    off += (bytes + 255) & ~(size_t)255;
    return p;
  };
  ushort* Mt   = (ushort*)alloc((size_t)D_ * D_ * 2);        // 1.18 MB
  ushort* wqb  = (ushort*)alloc((size_t)D_ * D_ * 2);        // 1.18 MB
  float*  xbuf = (float*) alloc((size_t)B_ * L_ * 4);        // 256 KB
  ushort* qm   = (ushort*)alloc((size_t)B_ * L_ * D_ * 2);   // 100.7 MB
  (void)ws_size; (void)in_sizes; (void)n_in; (void)out_size;

  k_wqb <<<D_ * D_ / 4 / 256,  256, 0, stream>>>(WQ, wqb);
  k_mtm <<<36,                 256, 0, stream>>>(WK, wqb, Mt);
  k_qm  <<<B_ * L_ / 128 * 6,  256, 0, stream>>>(ctx, Mt, qm);
  k_attn<<<B_,                1024, 0, stream>>>(qm, cand, cand_mask, ctx_mask, WV, xbuf);
  k_mlp <<<B_,                 128, 0, stream>>>(xbuf, W1, b1, W2, b2, out);
}